// Round 17
// baseline (114.181 us; speedup 1.0000x reference)
//
#include <hip/hip_runtime.h>
#include <stdint.h>

// MultiHeadAttention fused pipeline for MI355X (gfx950).
// B=2, T=2048, C=1024, H=16, Dh=64. All inputs fp32; compute in bf16 MFMA.
//
// ws layout (48 MiB):
//   [ 0MB) xb   : x as bf16 [4096][1024]     -- after attn: partial-O (bf16, 12.6MB)
//   [ 8MB) Wqt  : Wq^T bf16  \
//   [10MB) Wkt              -- contiguous [3072][1024] B^T for the fused QKV GEMM
//   [12MB) Wvt              /
//   [13MB) PM (fp32 768x128), [13.5MB) PL (fp32 768x128)   -- attn partials m/l
//   [14MB) Wpt  (LIVE until gemm_proj -- partials must stay below 14MB)
//   [16MB) Qb   : [32 head][2048 t][64 d] bf16  (PRE-SCALED by 0.125*log2e)
//   [24MB) Kb   : same layout (unscaled)
//   [32MB) Vb   : TRANSPOSED [32 head][64 d][2048 t] bf16
//   [40MB) Ab   : attention out [4096][1024] bf16

typedef unsigned short bfu;                               // bf16 bits
typedef unsigned int u32;
typedef short bf16x8 __attribute__((ext_vector_type(8))); // 8 bf16 (4 VGPRs)
typedef float f32x4 __attribute__((ext_vector_type(4)));
typedef float f32x16 __attribute__((ext_vector_type(16)));

#define DEVI static __device__ __forceinline__

DEVI bfu f2bf(float f) {  // round-to-nearest-even fp32 -> bf16 bits
  union { float f; unsigned u; } a; a.f = f;
  unsigned u = a.u;
  u += 0x7fffu + ((u >> 16) & 1u);
  return (bfu)(u >> 16);
}

DEVI float bf2f(bfu x) {
  union { u32 u; float f; } a; a.u = ((u32)x) << 16; return a.f;
}

DEVI void gld_lds16(const void* g, void* l) {
  __builtin_amdgcn_global_load_lds(
      (const __attribute__((address_space(1))) void*)g,
      (__attribute__((address_space(3))) void*)l, 16, 0, 0);
}

#define BAR_VM4()                                         \
  do {                                                    \
    asm volatile("s_waitcnt vmcnt(4)" ::: "memory");      \
    __builtin_amdgcn_s_barrier();                         \
    asm volatile("" ::: "memory");                        \
  } while (0)
#define BAR_VM2()                                         \
  do {                                                    \
    asm volatile("s_waitcnt vmcnt(2)" ::: "memory");      \
    __builtin_amdgcn_s_barrier();                         \
    asm volatile("" ::: "memory");                        \
  } while (0)
#define BAR_VM0()                                         \
  do {                                                    \
    asm volatile("s_waitcnt vmcnt(0)" ::: "memory");      \
    __builtin_amdgcn_s_barrier();                         \
    asm volatile("" ::: "memory");                        \
  } while (0)

// ---------------- prep kernels ----------------

__global__ __launch_bounds__(256) void conv_x(const float* __restrict__ x,
                                              bfu* __restrict__ xb) {
  const int n4 = (4096 * 1024) / 4;
  for (int i = blockIdx.x * 256 + threadIdx.x; i < n4; i += gridDim.x * 256) {
    float4 v = ((const float4*)x)[i];
    ushort4 p;
    p.x = f2bf(v.x); p.y = f2bf(v.y); p.z = f2bf(v.z); p.w = f2bf(v.w);
    ((ushort4*)xb)[i] = p;
  }
}

// convert + transpose a 1024x1024 fp32 [k][n] -> bf16 [n][k]
__global__ __launch_bounds__(256) void conv_w(
    const float* __restrict__ W0, const float* __restrict__ W1,
    const float* __restrict__ W2, const float* __restrict__ W3,
    bfu* __restrict__ T0, bfu* __restrict__ T1,
    bfu* __restrict__ T2, bfu* __restrict__ T3) {
  __shared__ bfu tile[64][65];
  const float* W; bfu* T;
  switch (blockIdx.z) {
    case 0:  W = W0; T = T0; break;
    case 1:  W = W1; T = T1; break;
    case 2:  W = W2; T = T2; break;
    default: W = W3; T = T3; break;
  }
  const int k0 = blockIdx.y * 64, n0 = blockIdx.x * 64;
  const int c = threadIdx.x & 63, r4 = threadIdx.x >> 6;
#pragma unroll
  for (int i = 0; i < 16; i++) {
    int row = r4 + i * 4;  // k-local
    tile[row][c] = f2bf(W[(size_t)(k0 + row) * 1024 + n0 + c]);
  }
  __syncthreads();
#pragma unroll
  for (int i = 0; i < 16; i++) {
    int row = r4 + i * 4;  // n-local
    T[(size_t)(n0 + row) * 1024 + k0 + c] = tile[c][row];
  }
}

// ======== fused QKV GEMM: 256^2 tile, 8-wave, 4-phase/K-tile, counted vmcnt ========
// (r14 bench-proven source, unchanged)

__global__ __launch_bounds__(512) void gemm_qkv256(
    const bfu* __restrict__ A, const bfu* __restrict__ Bt,
    bfu* __restrict__ Qb, bfu* __restrict__ Kb, bfu* __restrict__ Vb) {
  __shared__ __align__(16) bfu LDS[2 * 32768];   // 128 KB
  const int bid = blockIdx.x;
  const int xcd = bid & 7, i0 = bid >> 3;        // i0 0..23
  const int tx = i0 >> 1, ty = xcd * 2 + (i0 & 1);   // tx 0..11, ty 0..15
  const int z = tx >> 2;                         // 0=Q,1=K,2=V
  const int m0 = ty * 256, n0g = tx * 256;       // n0g = row in Bt[3072][1024]
  const int tid = threadIdx.x, wave = tid >> 6, lane = tid & 63;
  const int wr = wave >> 2, wc = wave & 3;       // wave grid 2M x 4N
  const int fr = lane & 15, fq = lane >> 4;
  const int rslot4 = fq ^ ((fr >> 1) & 3);       // T2 read-side swizzle

#define STAGE_HT(bufn, ktile, isB, kk)                                           \
  do {                                                                           \
    const bfu* srcb = (isB) ? Bt + (size_t)n0g * 1024 : A + (size_t)m0 * 1024;   \
    bfu* dstb = LDS + (bufn) * 32768 + ((isB) ? 16384 : 0) + (kk) * 8192;        \
    _Pragma("unroll")                                                            \
    for (int j_ = 0; j_ < 2; j_++) {                                             \
      int s_ = tid + j_ * 512;                                                   \
      int r_ = s_ >> 2, cg_ = (s_ & 3) ^ ((r_ >> 1) & 3);                        \
      gld_lds16(srcb + (size_t)r_ * 1024 + (ktile) * 64 + (kk) * 32 + cg_ * 8,   \
                dstb + s_ * 8);                                                  \
    }                                                                            \
  } while (0)

#define READ_B(kk)                                                               \
  _Pragma("unroll")                                                              \
  for (int n = 0; n < 4; n++)                                                    \
    bfv[n] = *(const bf16x8*)&bufc_p[16384 + (kk) * 8192 +                       \
              ((wc * 64 + n * 16 + fr) * 4 + rslot4) * 8];

#define READ_A(dst, mq, kk)                                                      \
  _Pragma("unroll")                                                              \
  for (int mm = 0; mm < 4; mm++)                                                 \
    dst[mm] = *(const bf16x8*)&bufc_p[(kk) * 8192 +                              \
              ((wr * 128 + ((mq) * 4 + mm) * 16 + fr) * 4 + rslot4) * 8];

#define MFMA_Q(afv, mq)                                                          \
  __builtin_amdgcn_s_setprio(1);                                                 \
  _Pragma("unroll")                                                              \
  for (int mm = 0; mm < 4; mm++)                                                 \
    _Pragma("unroll")                                                            \
    for (int n = 0; n < 4; n++)                                                  \
      acc[(mq) * 4 + mm][n] = __builtin_amdgcn_mfma_f32_16x16x32_bf16(           \
          afv[mm], bfv[n], acc[(mq) * 4 + mm][n], 0, 0, 0);                      \
  __builtin_amdgcn_s_setprio(0);

  f32x4 acc[8][4] = {};
  STAGE_HT(0, 0, 0, 0);   // A_k0
  STAGE_HT(0, 0, 1, 0);   // B_k0
  STAGE_HT(0, 0, 0, 1);   // A_k1
  STAGE_HT(0, 0, 1, 1);   // B_k1
  BAR_VM4();              // A_k0,B_k0 landed; A_k1,B_k1 in flight

  const int NT = 16;      // K=1024 / BK=64
  for (int t = 0; t < NT; t++) {
    const int more = (t + 1 < NT);
    const bfu* bufc_p = LDS + (t & 1) * 32768;
    const int bufn = (t & 1) ^ 1;
    bf16x8 bfv[4], afA[4], afB[4];
    // ---- k-half 0 (2 phases) ----
    READ_B(0);
    READ_A(afA, 0, 0);
    if (more) STAGE_HT(bufn, t + 1, 0, 0);   // A_k0(t+1)
    MFMA_Q(afA, 0);
    READ_A(afB, 1, 0);
    if (more) STAGE_HT(bufn, t + 1, 1, 0);   // B_k0(t+1)
    MFMA_Q(afB, 1);
    if (more) BAR_VM4();    // A_k1,B_k1(t) landed; k0(t+1) in flight
    else      BAR_VM0();    // last tile: drain own k1 halves
    // ---- k-half 1 (2 phases) ----
    READ_B(1);
    READ_A(afA, 0, 1);
    if (more) STAGE_HT(bufn, t + 1, 0, 1);   // A_k1(t+1)
    MFMA_Q(afA, 0);
    READ_A(afB, 1, 1);
    if (more) STAGE_HT(bufn, t + 1, 1, 1);   // B_k1(t+1)
    MFMA_Q(afB, 1);
    BAR_VM4();              // A_k0,B_k0(t+1) landed; k1(t+1) in flight
  }
#undef STAGE_HT
#undef READ_B
#undef READ_A
#undef MFMA_Q

  const float qs = (z == 0) ? 0.1803368801f : 1.0f;  // 0.125*log2e
#pragma unroll
  for (int mf = 0; mf < 8; mf++)
#pragma unroll
    for (int n = 0; n < 4; n++) {
      int r = m0 + wr * 128 + mf * 16 + fq * 4;            // global row
      int cwm = (tx & 3) * 256 + wc * 64 + n * 16 + fr;    // col within matrix
      int b = r >> 11, tt = r & 2047, h = cwm >> 6, d = cwm & 63;
      if (z == 0) {
        size_t base = ((size_t)(b * 16 + h) * 2048 + tt) * 64 + d;
#pragma unroll
        for (int i = 0; i < 4; i++)
          Qb[base + (size_t)i * 64] = f2bf(acc[mf][n][i] * qs);
      } else if (z == 1) {
        size_t base = ((size_t)(b * 16 + h) * 2048 + tt) * 64 + d;
#pragma unroll
        for (int i = 0; i < 4; i++)
          Kb[base + (size_t)i * 64] = f2bf(acc[mf][n][i]);
      } else {
        size_t base = ((size_t)(b * 16 + h) * 64 + d) * 2048 + tt;
        ushort4 p;
        p.x = f2bf(acc[mf][n][0]); p.y = f2bf(acc[mf][n][1]);
        p.z = f2bf(acc[mf][n][2]); p.w = f2bf(acc[mf][n][3]);
        *(ushort4*)&Vb[base] = p;
      }
    }
}

// ======== output projection v2: 128^2 tile, 8-wave, 4-phase/K-tile ========
// (r16 bench-proven source, unchanged)

__global__ __launch_bounds__(512) void gemm_proj(
    const bfu* __restrict__ A, const bfu* __restrict__ Bt,
    const float* __restrict__ bias, float* __restrict__ out) {
  __shared__ __align__(16) bfu LDS[2 * 16384];   // 64 KB
  const int bid = blockIdx.x;
  const int xcd = bid & 7, i0 = bid >> 3;        // i0 0..31
  const int tx = i0 >> 2, ty = xcd * 4 + (i0 & 3);   // tx 0..7, ty 0..31
  const int m0 = ty * 128, n0 = tx * 128;
  const int tid = threadIdx.x, wave = tid >> 6, lane = tid & 63;
  const int wr = wave >> 1, wc = wave & 1;       // wave grid 4M x 2N
  const int fr = lane & 15, fq = lane >> 4;
  const int rslot4 = fq ^ ((fr >> 1) & 3);       // T2 read-side swizzle

#define STAGE_HT(bufn, ktile, isB, kk)                                           \
  do {                                                                           \
    const bfu* srcb = (isB) ? Bt + (size_t)n0 * 1024 : A + (size_t)m0 * 1024;    \
    bfu* dstb = LDS + (bufn) * 16384 + ((isB) ? 8192 : 0) + (kk) * 4096;         \
    int r_ = tid >> 2, cg_ = (tid & 3) ^ ((r_ >> 1) & 3);                        \
    gld_lds16(srcb + (size_t)r_ * 1024 + (ktile) * 64 + (kk) * 32 + cg_ * 8,     \
              dstb + tid * 8);                                                   \
  } while (0)

#define READ_B(kk)                                                               \
  _Pragma("unroll")                                                              \
  for (int n = 0; n < 4; n++)                                                    \
    bfv[n] = *(const bf16x8*)&bufc_p[8192 + (kk) * 4096 +                        \
              ((wc * 64 + n * 16 + fr) * 4 + rslot4) * 8];

#define READ_A(kk)                                                               \
  _Pragma("unroll")                                                              \
  for (int mm = 0; mm < 2; mm++)                                                 \
    af[mm] = *(const bf16x8*)&bufc_p[(kk) * 4096 +                               \
              ((wr * 32 + mm * 16 + fr) * 4 + rslot4) * 8];

#define MFMA_H(nq)                                                               \
  __builtin_amdgcn_s_setprio(1);                                                 \
  _Pragma("unroll")                                                              \
  for (int mm = 0; mm < 2; mm++)                                                 \
    _Pragma("unroll")                                                            \
    for (int n = 0; n < 2; n++)                                                  \
      acc[mm][(nq) * 2 + n] = __builtin_amdgcn_mfma_f32_16x16x32_bf16(           \
          af[mm], bfv[(nq) * 2 + n], acc[mm][(nq) * 2 + n], 0, 0, 0);            \
  __builtin_amdgcn_s_setprio(0);

  f32x4 acc[2][4] = {};
  STAGE_HT(0, 0, 0, 0);   // A_k0
  STAGE_HT(0, 0, 1, 0);   // B_k0
  STAGE_HT(0, 0, 0, 1);   // A_k1
  STAGE_HT(0, 0, 1, 1);   // B_k1
  BAR_VM2();              // A_k0,B_k0 landed; A_k1,B_k1 in flight

  const int NT = 16;      // K=1024 / BK=64
  for (int t = 0; t < NT; t++) {
    const int more = (t + 1 < NT);
    const bfu* bufc_p = LDS + (t & 1) * 16384;
    const int bufn = (t & 1) ^ 1;
    bf16x8 bfv[4], af[2];
    // ---- k-half 0 ----
    READ_B(0);
    READ_A(0);
    if (more) STAGE_HT(bufn, t + 1, 0, 0);   // A_k0(t+1)
    MFMA_H(0);
    if (more) STAGE_HT(bufn, t + 1, 1, 0);   // B_k0(t+1)
    MFMA_H(1);
    if (more) BAR_VM2();    // A_k1,B_k1(t) landed; k0(t+1) in flight
    else      BAR_VM0();    // last tile: drain own k1 halves
    // ---- k-half 1 ----
    READ_B(1);
    READ_A(1);
    if (more) STAGE_HT(bufn, t + 1, 0, 1);   // A_k1(t+1)
    MFMA_H(0);
    if (more) STAGE_HT(bufn, t + 1, 1, 1);   // B_k1(t+1)
    MFMA_H(1);
    BAR_VM2();              // A_k0,B_k0(t+1) landed; k1(t+1) in flight
  }
#undef STAGE_HT
#undef READ_B
#undef READ_A
#undef MFMA_H

  // epilogue: fp32 + bias
#pragma unroll
  for (int mm = 0; mm < 2; mm++)
#pragma unroll
    for (int n = 0; n < 4; n++) {
      int r = m0 + wr * 32 + mm * 16 + fq * 4;
      int c = n0 + wc * 64 + n * 16 + fr;
      float bv = bias[c];
#pragma unroll
      for (int i = 0; i < 4; i++)
        out[(size_t)(r + i) * 1024 + c] = acc[mm][n][i] + bv;
    }
}

// ---- flash attention (causal) v12: split-K + 2-tile-per-barrier, 4-buffer LDS ----
// Per iteration: math for tiles (kb, kb+1), staging tiles (kb+2, kb+3) into
// buffers freed by the PREVIOUS barrier; ONE vmcnt(0)+barrier per 2 tiles.
// The drain is cheap: stages were issued 1400-2800 cyc earlier. Per-64-key
// math body is byte-identical to the r13-proven source (macro, static indices).

__global__ __launch_bounds__(256) void attn_fwd(
    const bfu* __restrict__ Q, const bfu* __restrict__ K,
    const bfu* __restrict__ Vt, bfu* __restrict__ Ob,
    bfu* __restrict__ PO, float* __restrict__ PM, float* __restrict__ PL) {
  __shared__ __align__(16) bfu Ks[4][4096];   // 8 KB each buf (64 keys x 64 d)
  __shared__ __align__(16) bfu Vs[4][4096];
  const int bid = blockIdx.x;
  const int xcd = bid & 7, i0 = bid >> 3;        // i0 0..127
  const int slot = i0 >> 5, cuL = i0 & 31;       // slot = dispatch pass
  const int head = cuL >> 3, cu8 = cuL & 7;
  const int hb = xcd * 4 + head;                 // head instance (= b*16+h)
  int qb, mode;                                  // mode 0=full,1=half0,2=half1
  if (slot < 2)      { qb = 15 - cu8; mode = slot + 1; }
  else if (cu8 < 4)  { if (slot == 3) return; qb = cu8; mode = 0; }
  else               { qb = cu8; mode = slot - 1; }
  const int kb0   = (mode == 2) ? (qb + 1) : 0;
  const int kbmax = (mode == 1) ? qb : (2 * qb + 1);
  const int tid = threadIdx.x, wave = tid >> 6, lane = tid & 63;
  const int q31 = lane & 31, hi = lane >> 5;
  const bfu* Qh = Q  + (size_t)hb * 2048 * 64;
  const bfu* Kh = K  + (size_t)hb * 2048 * 64;
  const bfu* Vh = Vt + (size_t)hb * 64 * 2048;
  const int b = hb >> 4, h = hb & 15;
  const int q0w = qb * 128 + wave * 32;          // this wave's 32 q rows
  const int qg = q0w + q31;

  // staging: 512 x 16B slots per tile; slot s -> row = s>>3, col-slot s&7 holds
  // global col-group (s&7) ^ (row&7) (XOR involution, linear LDS dest).
  const int r0 = tid >> 3, r1 = (256 + tid) >> 3;
  const int c0 = (tid & 7) ^ (r0 & 7), c1 = (tid & 7) ^ (r1 & 7);
#define STAGE_K(bufi, kbase)                                                          \
  do {                                                                                \
    gld_lds16(Kh + (size_t)((kbase) + r0) * 64 + c0 * 8, &Ks[bufi][tid * 8]);         \
    gld_lds16(Kh + (size_t)((kbase) + r1) * 64 + c1 * 8, &Ks[bufi][(256 + tid) * 8]); \
  } while (0)
#define STAGE_V(bufi, kbase)                                                          \
  do {                                                                                \
    gld_lds16(Vh + (size_t)r0 * 2048 + (kbase) + c0 * 8, &Vs[bufi][tid * 8]);         \
    gld_lds16(Vh + (size_t)r1 * 2048 + (kbase) + c1 * 8, &Vs[bufi][(256 + tid) * 8]); \
  } while (0)

  // Q as B-frags (4 d-chunks): B[d=8*hi+j][q=lane&31]
  bf16x8 qv[4];
#pragma unroll
  for (int c = 0; c < 4; c++)
    qv[c] = *(const bf16x8*)&Qh[(size_t)(q0w + q31) * 64 + c * 16 + hi * 8];

  bf16x8 onesv;
#pragma unroll
  for (int j = 0; j < 8; j++) onesv[j] = (short)0x3F80;  // bf16 1.0

  f32x16 o0 = {}, o1 = {}, lac = {};
  float m = -1e30f;

// one 64-key tile: QK^T + softmax + pack + PV, with stage hooks interleaved.
// HOOK1 before QK, HOOK2 before PV, HOOK3 after PV. Math = r13-proven body.
#define TILE64(kbase_, KsC_, VsC_, HOOK1, HOOK2, HOOK3)                               \
  do {                                                                                \
    const int kbase = (kbase_);                                                       \
    const bfu* KsC = (KsC_);                                                          \
    const bfu* VsC = (VsC_);                                                          \
    const int active = (kbase <= q0w + 31);                                           \
    HOOK1;                                                                            \
    u32 W0[8], W1[8];                                                                 \
    if (active) {                                                                     \
      f32x16 s0 = {}, s1 = {};                                                        \
      _Pragma("unroll")                                                               \
      for (int c = 0; c < 4; c++) {                                                   \
        const int g = 2 * c + hi;                                                     \
        bf16x8 kf0 = *(const bf16x8*)&KsC[(q31 * 8 + (g ^ (q31 & 7))) * 8];           \
        bf16x8 kf1 = *(const bf16x8*)&KsC[((32 + q31) * 8 + (g ^ (q31 & 7))) * 8];    \
        s0 = __builtin_amdgcn_mfma_f32_32x32x16_bf16(kf0, qv[c], s0, 0, 0, 0);        \
        s1 = __builtin_amdgcn_mfma_f32_32x32x16_bf16(kf1, qv[c], s1, 0, 0, 0);        \
      }                                                                               \
      if (kbase + 63 > q0w) {                                                         \
        _Pragma("unroll")                                                             \
        for (int r = 0; r < 16; r++) {                                                \
          int krow = (r & 3) + 8 * (r >> 2) + 4 * hi;                                 \
          if (kbase + krow > qg)      s0[r] = -1e30f;                                 \
          if (kbase + 32 + krow > qg) s1[r] = -1e30f;                                 \
        }                                                                             \
      }                                                                               \
      float pm = s0[0];                                                               \
      _Pragma("unroll")                                                               \
      for (int r = 1; r < 16; r++) pm = fmaxf(pm, s0[r]);                             \
      _Pragma("unroll")                                                               \
      for (int r = 0; r < 16; r++) pm = fmaxf(pm, s1[r]);                             \
      pm = fmaxf(pm, __shfl_xor(pm, 32));                                             \
      if (!__all(pm <= m + 8.0f)) {                                                   \
        float mn = fmaxf(m, pm);                                                      \
        float al = __builtin_amdgcn_exp2f(m - mn);                                    \
        m = mn;                                                                       \
        _Pragma("unroll")                                                             \
        for (int r = 0; r < 16; r++) {                                                \
          float alq = __shfl(al, (r & 3) + 8 * (r >> 2) + 4 * hi);                    \
          o0[r] *= alq; o1[r] *= alq; lac[r] *= alq;                                  \
        }                                                                             \
      }                                                                               \
      _Pragma("unroll")                                                               \
      for (int w = 0; w < 8; w++) {                                                   \
        float a0 = __builtin_amdgcn_exp2f(s0[2 * w] - m);                             \
        float a1 = __builtin_amdgcn_exp2f(s0[2 * w + 1] - m);                         \
        asm("v_cvt_pk_bf16_f32 %0, %1, %2" : "=v"(W0[w]) : "v"(a0), "v"(a1));         \
        float b0 = __builtin_amdgcn_exp2f(s1[2 * w] - m);                             \
        float b1 = __builtin_amdgcn_exp2f(s1[2 * w + 1] - m);                         \
        asm("v_cvt_pk_bf16_f32 %0, %1, %2" : "=v"(W1[w]) : "v"(b0), "v"(b1));         \
      }                                                                               \
    }                                                                                 \
    HOOK2;                                                                            \
    if (active) {                                                                     \
      __builtin_amdgcn_s_setprio(1);                                                  \
      _Pragma("unroll")                                                               \
      for (int c = 0; c < 4; c++) {                                                   \
        const u32* Wsel = (c < 2) ? W0 : W1;                                          \
        const int w0 = 4 * (c & 1);                                                   \
        u32 t0 = Wsel[w0],     t2 = Wsel[w0 + 2];                                     \
        u32 t1 = Wsel[w0 + 1], t3 = Wsel[w0 + 3];                                     \
        asm("v_permlane32_swap_b32 %0, %1" : "+v"(t0), "+v"(t2));                     \
        asm("v_permlane32_swap_b32 %0, %1" : "+v"(t1), "+v"(t3));                     \
        union { u32 u[4]; bf16x8 v; } pa;                                             \
        pa.u[0] = t0; pa.u[1] = t1; pa.u[2] = t2; pa.u[3] = t3;                       \
        const int g = 2 * c + hi;                                                     \
        bf16x8 vb0 = *(const bf16x8*)&VsC[(q31 * 8 + (g ^ (q31 & 7))) * 8];           \
        bf16x8 vb1 = *(const bf16x8*)&VsC[((32 + q31) * 8 + (g ^ (q31 & 7))) * 8];    \
        o0  = __builtin_amdgcn_mfma_f32_32x32x16_bf16(pa.v, vb0,   o0,  0, 0, 0);     \
        o1  = __builtin_amdgcn_mfma_f32_32x32x16_bf16(pa.v, vb1,   o1,  0, 0, 0);     \
        lac = __builtin_amdgcn_mfma_f32_32x32x16_bf16(pa.v, onesv, lac, 0, 0, 0);     \
      }                                                                               \
      __builtin_amdgcn_s_setprio(0);                                                  \
    }                                                                                 \
    HOOK3;                                                                            \
  } while (0)

  // prologue: ranges always have >= 2 tiles (mode0: 2qb+2 >= 2; mode1/2: qb+1 >= 5).
  STAGE_K(0, kb0 * 64);
  STAGE_V(0, kb0 * 64);
  STAGE_K(1, (kb0 + 1) * 64);
  STAGE_V(1, (kb0 + 1) * 64);
  BAR_VM0();   // tiles kb0, kb0+1 resident

  for (int kb = kb0; kb <= kbmax; kb += 2) {
    const int idx = kb - kb0;
    const int bA = idx & 3, bB = (idx + 1) & 3;
    const int b2 = (idx + 2) & 3, b3 = (idx + 3) & 3;
    const int have1 = (kb + 1 <= kbmax);
    const int pre2 = (kb + 2 <= kbmax), pre3 = (kb + 3 <= kbmax);
    // tile kb: stage (kb+2) and (kb+3) interleaved into its math
    TILE64(kb * 64, Ks[bA], Vs[bA],
           { if (pre2) STAGE_K(b2, (kb + 2) * 64); },
           { if (pre2) STAGE_V(b2, (kb + 2) * 64);
             if (pre3) STAGE_K(b3, (kb + 3) * 64); },
           { if (pre3) STAGE_V(b3, (kb + 3) * 64); });
    // tile kb+1: no staging (already issued), pure math
    if (have1)
      TILE64((kb + 1) * 64, Ks[bB], Vs[bB],
             ((void)0), ((void)0), ((void)0));
    BAR_VM0();   // drain (kb+2,kb+3) stages (issued ~1-2 tiles earlier) + reuse guard
  }
#undef TILE64
#undef STAGE_K
#undef STAGE_V

  if (mode == 0) {
    // direct epilogue: Ob[b*2048+t][h*64+d]
#pragma unroll
    for (int r = 0; r < 16; r++) {
      int t = q0w + (r & 3) + 8 * (r >> 2) + 4 * hi;
      float inv = 1.0f / lac[r];
      size_t base = (size_t)(b * 2048 + t) * 1024 + h * 64;
      Ob[base + q31]      = f2bf(o0[r] * inv);
      Ob[base + 32 + q31] = f2bf(o1[r] * inv);
    }
  } else {
    // partial epilogue: p in [0,768); o as bf16 [128][64], m/l fp32 [128]
    const int p = (hb * 12 + (qb - 4)) * 2 + (mode - 1);
    bfu*   po = PO + (size_t)p * 8192;
    float* pmv = PM + p * 128;
    float* plv = PL + p * 128;
    pmv[wave * 32 + q31] = m;
#pragma unroll
    for (int r = 0; r < 16; r++) {
      int rm = (r & 3) + 8 * (r >> 2) + 4 * hi;
      plv[wave * 32 + rm] = lac[r];
      po[(wave * 32 + rm) * 64 + q31]      = f2bf(o0[r]);
      po[(wave * 32 + rm) * 64 + 32 + q31] = f2bf(o1[r]);
    }
  }
}

// combine the two equal halves for qb>=4: 384 WGs = (hb, qb-4).
__global__ __launch_bounds__(256) void attn_comb(
    const bfu* __restrict__ PO, const float* __restrict__ PM,
    const float* __restrict__ PL, bfu* __restrict__ Ob) {
  const int g = blockIdx.x;            // 0..383
  const int hb = g / 12, j = g % 12, qb = j + 4;
  const int b = hb >> 4, h = hb & 15;
  const int p0 = g * 2, p1 = p0 + 1;
  const int tid = threadIdx.x;
  const int r = tid >> 1, ch = tid & 1;          // row 0..127, col-half
  float m0 = PM[p0 * 128 + r], m1 = PM[p1 * 128 + r];
  float l0 = PL[p0 * 128 + r], l1 = PL[p1 * 128 + r];
  float ms = fmaxf(m0, m1);
  float f0 = __builtin_amdgcn_exp2f(m0 - ms);
  float f1 = __builtin_amdgcn_exp2f(m1 - ms);
  float inv = 1.0f / (l0 * f0 + l1 * f1);
  const bfu* a0 = PO + (size_t)p0 * 8192 + r * 64 + ch * 32;
  const bfu* a1 = PO + (size_t)p1 * 8192 + r * 64 + ch * 32;
  const int t = qb * 128 + r;
  bfu* ob = Ob + (size_t)(b * 2048 + t) * 1024 + h * 64 + ch * 32;
#pragma unroll
  for (int k = 0; k < 4; k++) {
    bf16x8 v0 = *(const bf16x8*)(a0 + k * 8);
    bf16x8 v1 = *(const bf16x8*)(a1 + k * 8);
    bf16x8 vo;
#pragma unroll
    for (int e = 0; e < 8; e++) {
      float acc = bf2f((bfu)(unsigned short)v0[e]) * f0 +
                  bf2f((bfu)(unsigned short)v1[e]) * f1;
      vo[e] = (short)f2bf(acc * inv);
    }
    *(bf16x8*)(ob + k * 8) = vo;
  }
}

// ---------------- launch ----------------

extern "C" void kernel_launch(void* const* d_in, const int* in_sizes, int n_in,
                              void* d_out, int out_size, void* d_ws, size_t ws_size,
                              hipStream_t stream) {
  const float* x  = (const float*)d_in[0];
  const float* Wk = (const float*)d_in[1];  // note dict order: Wk before Wq!
  const float* Wq = (const float*)d_in[2];
  const float* Wv = (const float*)d_in[3];
  const float* Wp = (const float*)d_in[4];
  const float* bp = (const float*)d_in[5];
  char* ws = (char*)d_ws;
  bfu* xb  = (bfu*)(ws);
  bfu* Wqt = (bfu*)(ws + ( 8u << 20));   // start of contiguous [3072][1024] B^T
  bfu* Wkt = (bfu*)(ws + (10u << 20));
  bfu* Wvt = (bfu*)(ws + (12u << 20));
  bfu* Wpt = (bfu*)(ws + (14u << 20));
  bfu* Qb  = (bfu*)(ws + (16u << 20));
  bfu* Kb  = (bfu*)(ws + (24u << 20));
  bfu* Vb  = (bfu*)(ws + (32u << 20));
  bfu* Ab  = (bfu*)(ws + (40u << 20));
  bfu*   PO = (bfu*)(ws);                         // 768 x 8192 bf16 = 12.6 MB
  float* PM = (float*)(ws + (13u << 20));         // 768 x 128 fp32
  float* PL = (float*)(ws + (13u << 20) + (512u << 10));  // +0.5 MB
  float* out = (float*)d_out;

  conv_x<<<1024, 256, 0, stream>>>(x, xb);
  conv_w<<<dim3(16, 16, 4), 256, 0, stream>>>(Wq, Wk, Wv, Wp, Wqt, Wkt, Wvt, Wpt);
  gemm_qkv256<<<192, 512, 0, stream>>>(xb, Wqt, Qb, Kb, Vb);
  attn_fwd<<<1024, 256, 0, stream>>>(Qb, Kb, Vb, Ab, PO, PM, PL);
  attn_comb<<<384, 256, 0, stream>>>(PO, PM, PL, Ab);
  gemm_proj<<<256, 512, 0, stream>>>(Ab, Wpt, bp, out);
}

// Round 18
// 111.435 us; speedup vs baseline: 1.0246x; 1.0246x over previous
//
#include <hip/hip_runtime.h>
#include <stdint.h>

// MultiHeadAttention fused pipeline for MI355X (gfx950).
// B=2, T=2048, C=1024, H=16, Dh=64. All inputs fp32; compute in bf16 MFMA.
//
// ws layout (48 MiB):
//   [ 0MB) xb   : x as bf16 [4096][1024]     -- after attn: partial-O (bf16, 12.6MB)
//   [ 8MB) Wqt  : Wq^T bf16  \
//   [10MB) Wkt              -- contiguous [3072][1024] B^T for the fused QKV GEMM
//   [12MB) Wvt              /
//   [13MB) PM (fp32 768x128), [13.5MB) PL (fp32 768x128)   -- attn partials m/l
//   [14MB) Wpt  (LIVE until gemm_proj -- partials must stay below 14MB)
//   [16MB) Qb   : [32 head][2048 t][64 d] bf16  (PRE-SCALED by 0.125*log2e)
//   [24MB) Kb   : same layout (unscaled)
//   [32MB) Vb   : TRANSPOSED [32 head][64 d][2048 t] bf16
//   [40MB) Ab   : attention out [4096][1024] bf16

typedef unsigned short bfu;                               // bf16 bits
typedef unsigned int u32;
typedef short bf16x8 __attribute__((ext_vector_type(8))); // 8 bf16 (4 VGPRs)
typedef float f32x4 __attribute__((ext_vector_type(4)));
typedef float f32x16 __attribute__((ext_vector_type(16)));

#define DEVI static __device__ __forceinline__

DEVI bfu f2bf(float f) {  // round-to-nearest-even fp32 -> bf16 bits
  union { float f; unsigned u; } a; a.f = f;
  unsigned u = a.u;
  u += 0x7fffu + ((u >> 16) & 1u);
  return (bfu)(u >> 16);
}

DEVI float bf2f(bfu x) {
  union { u32 u; float f; } a; a.u = ((u32)x) << 16; return a.f;
}

DEVI void gld_lds16(const void* g, void* l) {
  __builtin_amdgcn_global_load_lds(
      (const __attribute__((address_space(1))) void*)g,
      (__attribute__((address_space(3))) void*)l, 16, 0, 0);
}

#define BAR_VMN(N)                                        \
  do {                                                    \
    asm volatile("s_waitcnt vmcnt(" #N ")" ::: "memory"); \
    __builtin_amdgcn_s_barrier();                         \
    asm volatile("" ::: "memory");                        \
  } while (0)
#define BAR_VM5() BAR_VMN(5)
#define BAR_VM4() BAR_VMN(4)
#define BAR_VM2() BAR_VMN(2)
#define BAR_VM0() BAR_VMN(0)

// ---------------- prep kernels ----------------

__global__ __launch_bounds__(256) void conv_x(const float* __restrict__ x,
                                              bfu* __restrict__ xb) {
  const int n4 = (4096 * 1024) / 4;
  for (int i = blockIdx.x * 256 + threadIdx.x; i < n4; i += gridDim.x * 256) {
    float4 v = ((const float4*)x)[i];
    ushort4 p;
    p.x = f2bf(v.x); p.y = f2bf(v.y); p.z = f2bf(v.z); p.w = f2bf(v.w);
    ((ushort4*)xb)[i] = p;
  }
}

// convert + transpose a 1024x1024 fp32 [k][n] -> bf16 [n][k]
__global__ __launch_bounds__(256) void conv_w(
    const float* __restrict__ W0, const float* __restrict__ W1,
    const float* __restrict__ W2, const float* __restrict__ W3,
    bfu* __restrict__ T0, bfu* __restrict__ T1,
    bfu* __restrict__ T2, bfu* __restrict__ T3) {
  __shared__ bfu tile[64][65];
  const float* W; bfu* T;
  switch (blockIdx.z) {
    case 0:  W = W0; T = T0; break;
    case 1:  W = W1; T = T1; break;
    case 2:  W = W2; T = T2; break;
    default: W = W3; T = T3; break;
  }
  const int k0 = blockIdx.y * 64, n0 = blockIdx.x * 64;
  const int c = threadIdx.x & 63, r4 = threadIdx.x >> 6;
#pragma unroll
  for (int i = 0; i < 16; i++) {
    int row = r4 + i * 4;  // k-local
    tile[row][c] = f2bf(W[(size_t)(k0 + row) * 1024 + n0 + c]);
  }
  __syncthreads();
#pragma unroll
  for (int i = 0; i < 16; i++) {
    int row = r4 + i * 4;  // n-local
    T[(size_t)(n0 + row) * 1024 + k0 + c] = tile[c][row];
  }
}

// ======== fused QKV GEMM v2: 256x192 tile, grid 256 (1 WG/CU), 8-wave ========
// C[4096,3072] = xb . BtAll^T. BN=192 -> 16x16 = 256 blocks (no idle CUs).
// LDS 112KB: 2 buffers x {A_k0 16KB, A_k1 16KB, B full-tile 24KB}.
// A staged per k-half (2 loads/thread); B staged as full 64-K tile (3 loads/
// thread, uniform). Counted-vmcnt ladder: half-boundary vmcnt(5) (A_k0+B of
// t+1 in flight), tile-end vmcnt(2) (A_k1(t+1) in flight). T2 swizzle as r14.

__global__ __launch_bounds__(512) void gemm_qkv192(
    const bfu* __restrict__ A, const bfu* __restrict__ Bt,
    bfu* __restrict__ Qb, bfu* __restrict__ Kb, bfu* __restrict__ Vb) {
  __shared__ __align__(16) bfu LDS[2 * 28672];   // 112 KB
  const int bid = blockIdx.x;
  const int xcd = bid & 7, i0 = bid >> 3;        // i0 0..31
  const int ty = xcd * 2 + (i0 & 1), tx = i0 >> 1;   // ty 0..15, tx 0..15
  const int m0 = ty * 256, n0g = tx * 192;
  const int tid = threadIdx.x, wave = tid >> 6, lane = tid & 63;
  const int wr = wave >> 2, wc = wave & 3;       // wave grid 2M x 4N (128x48/wave)
  const int fr = lane & 15, fq = lane >> 4;
  const int rslot4 = fq ^ ((fr >> 1) & 3);       // T2 read-side swizzle

  // A half-tile: 1024 slots (256 rows x 4), 2 loads/thread.
#define STAGE_A(bufn, ktile, kk)                                                 \
  do {                                                                           \
    _Pragma("unroll")                                                            \
    for (int j_ = 0; j_ < 2; j_++) {                                             \
      int s_ = tid + j_ * 512;                                                   \
      int r_ = s_ >> 2, cg_ = (s_ & 3) ^ ((r_ >> 1) & 3);                        \
      gld_lds16(A + (size_t)(m0 + r_) * 1024 + (ktile) * 64 + (kk) * 32 + cg_ * 8,\
                LDS + (bufn) * 28672 + (kk) * 8192 + s_ * 8);                    \
    }                                                                            \
  } while (0)
  // B full tile: 1536 slots (2 k-halves x 192 rows x 4), 3 loads/thread.
#define STAGE_B(bufn, ktile)                                                     \
  do {                                                                           \
    _Pragma("unroll")                                                            \
    for (int j_ = 0; j_ < 3; j_++) {                                             \
      int s_ = tid + j_ * 512;                                                   \
      int kk_ = (s_ >= 768) ? 1 : 0;                                             \
      int sp_ = s_ - kk_ * 768;                                                  \
      int r_ = sp_ >> 2, cg_ = (sp_ & 3) ^ ((r_ >> 1) & 3);                      \
      gld_lds16(Bt + (size_t)(n0g + r_) * 1024 + (ktile) * 64 + kk_ * 32 + cg_ * 8,\
                LDS + (bufn) * 28672 + 16384 + s_ * 8);                          \
    }                                                                            \
  } while (0)

#define READ_B(kk)                                                               \
  _Pragma("unroll")                                                              \
  for (int n = 0; n < 3; n++)                                                    \
    bfv[n] = *(const bf16x8*)&bufc_p[16384 + (kk) * 6144 +                       \
              ((wc * 48 + n * 16 + fr) * 4 + rslot4) * 8];

#define READ_A(dst, mq, kk)                                                      \
  _Pragma("unroll")                                                              \
  for (int mm = 0; mm < 4; mm++)                                                 \
    dst[mm] = *(const bf16x8*)&bufc_p[(kk) * 8192 +                              \
              ((wr * 128 + ((mq) * 4 + mm) * 16 + fr) * 4 + rslot4) * 8];

#define MFMA_Q(afv, mq)                                                          \
  __builtin_amdgcn_s_setprio(1);                                                 \
  _Pragma("unroll")                                                              \
  for (int mm = 0; mm < 4; mm++)                                                 \
    _Pragma("unroll")                                                            \
    for (int n = 0; n < 3; n++)                                                  \
      acc[(mq) * 4 + mm][n] = __builtin_amdgcn_mfma_f32_16x16x32_bf16(           \
          afv[mm], bfv[n], acc[(mq) * 4 + mm][n], 0, 0, 0);                      \
  __builtin_amdgcn_s_setprio(0);

  f32x4 acc[8][3] = {};
  // prologue: A_k0(0)[2], B(0)[3], A_k1(0)[2]; wait A_k0+B landed, A_k1 in flight.
  STAGE_A(0, 0, 0);
  STAGE_B(0, 0);
  STAGE_A(0, 0, 1);
  BAR_VM2();

  const int NT = 16;      // K=1024 / BK=64
  for (int t = 0; t < NT; t++) {
    const int more = (t + 1 < NT);
    const bfu* bufc_p = LDS + (t & 1) * 28672;
    const int bufn = (t & 1) ^ 1;
    bf16x8 bfv[3], afA[4], afB[4];
    // ---- k-half 0 ----
    READ_B(0);
    READ_A(afA, 0, 0);
    if (more) STAGE_A(bufn, t + 1, 0);   // 2 loads
    MFMA_Q(afA, 0);
    READ_A(afB, 1, 0);
    if (more) STAGE_B(bufn, t + 1);      // 3 loads
    MFMA_Q(afB, 1);
    if (more) BAR_VM5();    // A_k1(t) landed; A_k0(t+1)+B(t+1) in flight
    else      BAR_VM0();    // last tile: drain own A_k1
    // ---- k-half 1 ----
    READ_B(1);
    READ_A(afA, 0, 1);
    if (more) STAGE_A(bufn, t + 1, 1);   // 2 loads
    MFMA_Q(afA, 0);
    READ_A(afB, 1, 1);
    MFMA_Q(afB, 1);
    if (more) BAR_VM2();    // A_k0(t+1)+B(t+1) landed; A_k1(t+1) in flight
    else      BAR_VM0();
  }
#undef STAGE_A
#undef STAGE_B
#undef READ_B
#undef READ_A
#undef MFMA_Q

  // epilogue: per-element Q|K|V straddle (col C in [0,3072))
  const float qs = 0.1803368801f;  // 0.125*log2e (Q only)
#pragma unroll
  for (int mf = 0; mf < 8; mf++)
#pragma unroll
    for (int n = 0; n < 3; n++) {
      int r = m0 + wr * 128 + mf * 16 + fq * 4;      // global row
      int C = n0g + wc * 48 + n * 16 + fr;           // global col 0..3071
      int z = C >> 10, cwm = C & 1023;
      int b = r >> 11, tt = r & 2047, h = cwm >> 6, d = cwm & 63;
      if (z == 0) {
        size_t base = ((size_t)(b * 16 + h) * 2048 + tt) * 64 + d;
#pragma unroll
        for (int i = 0; i < 4; i++)
          Qb[base + (size_t)i * 64] = f2bf(acc[mf][n][i] * qs);
      } else if (z == 1) {
        size_t base = ((size_t)(b * 16 + h) * 2048 + tt) * 64 + d;
#pragma unroll
        for (int i = 0; i < 4; i++)
          Kb[base + (size_t)i * 64] = f2bf(acc[mf][n][i]);
      } else {
        size_t base = ((size_t)(b * 16 + h) * 64 + d) * 2048 + tt;
        ushort4 p;
        p.x = f2bf(acc[mf][n][0]); p.y = f2bf(acc[mf][n][1]);
        p.z = f2bf(acc[mf][n][2]); p.w = f2bf(acc[mf][n][3]);
        *(ushort4*)&Vb[base] = p;
      }
    }
}

// ======== output projection v2: 128^2 tile, 8-wave, 4-phase/K-tile ========
// (r16 bench-proven source, unchanged)

__global__ __launch_bounds__(512) void gemm_proj(
    const bfu* __restrict__ A, const bfu* __restrict__ Bt,
    const float* __restrict__ bias, float* __restrict__ out) {
  __shared__ __align__(16) bfu LDS[2 * 16384];   // 64 KB
  const int bid = blockIdx.x;
  const int xcd = bid & 7, i0 = bid >> 3;        // i0 0..31
  const int tx = i0 >> 2, ty = xcd * 4 + (i0 & 3);   // tx 0..7, ty 0..31
  const int m0 = ty * 128, n0 = tx * 128;
  const int tid = threadIdx.x, wave = tid >> 6, lane = tid & 63;
  const int wr = wave >> 1, wc = wave & 1;       // wave grid 4M x 2N
  const int fr = lane & 15, fq = lane >> 4;
  const int rslot4 = fq ^ ((fr >> 1) & 3);       // T2 read-side swizzle

#define STAGE_HT(bufn, ktile, isB, kk)                                           \
  do {                                                                           \
    const bfu* srcb = (isB) ? Bt + (size_t)n0 * 1024 : A + (size_t)m0 * 1024;    \
    bfu* dstb = LDS + (bufn) * 16384 + ((isB) ? 8192 : 0) + (kk) * 4096;         \
    int r_ = tid >> 2, cg_ = (tid & 3) ^ ((r_ >> 1) & 3);                        \
    gld_lds16(srcb + (size_t)r_ * 1024 + (ktile) * 64 + (kk) * 32 + cg_ * 8,     \
              dstb + tid * 8);                                                   \
  } while (0)

#define READ_B(kk)                                                               \
  _Pragma("unroll")                                                              \
  for (int n = 0; n < 4; n++)                                                    \
    bfv[n] = *(const bf16x8*)&bufc_p[8192 + (kk) * 4096 +                        \
              ((wc * 64 + n * 16 + fr) * 4 + rslot4) * 8];

#define READ_A(kk)                                                               \
  _Pragma("unroll")                                                              \
  for (int mm = 0; mm < 2; mm++)                                                 \
    af[mm] = *(const bf16x8*)&bufc_p[(kk) * 4096 +                               \
              ((wr * 32 + mm * 16 + fr) * 4 + rslot4) * 8];

#define MFMA_H(nq)                                                               \
  __builtin_amdgcn_s_setprio(1);                                                 \
  _Pragma("unroll")                                                              \
  for (int mm = 0; mm < 2; mm++)                                                 \
    _Pragma("unroll")                                                            \
    for (int n = 0; n < 2; n++)                                                  \
      acc[mm][(nq) * 2 + n] = __builtin_amdgcn_mfma_f32_16x16x32_bf16(           \
          af[mm], bfv[(nq) * 2 + n], acc[mm][(nq) * 2 + n], 0, 0, 0);            \
  __builtin_amdgcn_s_setprio(0);

  f32x4 acc[2][4] = {};
  STAGE_HT(0, 0, 0, 0);   // A_k0
  STAGE_HT(0, 0, 1, 0);   // B_k0
  STAGE_HT(0, 0, 0, 1);   // A_k1
  STAGE_HT(0, 0, 1, 1);   // B_k1
  BAR_VM2();              // A_k0,B_k0 landed; A_k1,B_k1 in flight

  const int NT = 16;      // K=1024 / BK=64
  for (int t = 0; t < NT; t++) {
    const int more = (t + 1 < NT);
    const bfu* bufc_p = LDS + (t & 1) * 16384;
    const int bufn = (t & 1) ^ 1;
    bf16x8 bfv[4], af[2];
    // ---- k-half 0 ----
    READ_B(0);
    READ_A(0);
    if (more) STAGE_HT(bufn, t + 1, 0, 0);   // A_k0(t+1)
    MFMA_H(0);
    if (more) STAGE_HT(bufn, t + 1, 1, 0);   // B_k0(t+1)
    MFMA_H(1);
    if (more) BAR_VM2();    // A_k1,B_k1(t) landed; k0(t+1) in flight
    else      BAR_VM0();    // last tile: drain own k1 halves
    // ---- k-half 1 ----
    READ_B(1);
    READ_A(1);
    if (more) STAGE_HT(bufn, t + 1, 0, 1);   // A_k1(t+1)
    MFMA_H(0);
    if (more) STAGE_HT(bufn, t + 1, 1, 1);   // B_k1(t+1)
    MFMA_H(1);
    BAR_VM2();              // A_k0,B_k0(t+1) landed; k1(t+1) in flight
  }
#undef STAGE_HT
#undef READ_B
#undef READ_A
#undef MFMA_H

  // epilogue: fp32 + bias
#pragma unroll
  for (int mm = 0; mm < 2; mm++)
#pragma unroll
    for (int n = 0; n < 4; n++) {
      int r = m0 + wr * 32 + mm * 16 + fq * 4;
      int c = n0 + wc * 64 + n * 16 + fr;
      float bv = bias[c];
#pragma unroll
      for (int i = 0; i < 4; i++)
        out[(size_t)(r + i) * 1024 + c] = acc[mm][n][i] + bv;
    }
}

// ---- flash attention (causal) v11: split-K schedule + TRIPLE-buffer counted
// vmcnt with per-phase stage interleave (r16 bench-proven source, unchanged).

__global__ __launch_bounds__(256) void attn_fwd(
    const bfu* __restrict__ Q, const bfu* __restrict__ K,
    const bfu* __restrict__ Vt, bfu* __restrict__ Ob,
    bfu* __restrict__ PO, float* __restrict__ PM, float* __restrict__ PL) {
  __shared__ __align__(16) bfu Ks[3][4096];   // 8 KB each buf (64 keys x 64 d)
  __shared__ __align__(16) bfu Vs[3][4096];
  const int bid = blockIdx.x;
  const int xcd = bid & 7, i0 = bid >> 3;        // i0 0..127
  const int slot = i0 >> 5, cuL = i0 & 31;       // slot = dispatch pass
  const int head = cuL >> 3, cu8 = cuL & 7;
  const int hb = xcd * 4 + head;                 // head instance (= b*16+h)
  int qb, mode;                                  // mode 0=full,1=half0,2=half1
  if (slot < 2)      { qb = 15 - cu8; mode = slot + 1; }
  else if (cu8 < 4)  { if (slot == 3) return; qb = cu8; mode = 0; }
  else               { qb = cu8; mode = slot - 1; }
  const int kb0   = (mode == 2) ? (qb + 1) : 0;
  const int kbmax = (mode == 1) ? qb : (2 * qb + 1);
  const int tid = threadIdx.x, wave = tid >> 6, lane = tid & 63;
  const int q31 = lane & 31, hi = lane >> 5;
  const bfu* Qh = Q  + (size_t)hb * 2048 * 64;
  const bfu* Kh = K  + (size_t)hb * 2048 * 64;
  const bfu* Vh = Vt + (size_t)hb * 64 * 2048;
  const int b = hb >> 4, h = hb & 15;
  const int q0w = qb * 128 + wave * 32;          // this wave's 32 q rows
  const int qg = q0w + q31;

  const int r0 = tid >> 3, r1 = (256 + tid) >> 3;
  const int c0 = (tid & 7) ^ (r0 & 7), c1 = (tid & 7) ^ (r1 & 7);
#define STAGE_K(bufi, kbase)                                                          \
  do {                                                                                \
    gld_lds16(Kh + (size_t)((kbase) + r0) * 64 + c0 * 8, &Ks[bufi][tid * 8]);         \
    gld_lds16(Kh + (size_t)((kbase) + r1) * 64 + c1 * 8, &Ks[bufi][(256 + tid) * 8]); \
  } while (0)
#define STAGE_V(bufi, kbase)                                                          \
  do {                                                                                \
    gld_lds16(Vh + (size_t)r0 * 2048 + (kbase) + c0 * 8, &Vs[bufi][tid * 8]);         \
    gld_lds16(Vh + (size_t)r1 * 2048 + (kbase) + c1 * 8, &Vs[bufi][(256 + tid) * 8]); \
  } while (0)

  bf16x8 qv[4];
#pragma unroll
  for (int c = 0; c < 4; c++)
    qv[c] = *(const bf16x8*)&Qh[(size_t)(q0w + q31) * 64 + c * 16 + hi * 8];

  bf16x8 onesv;
#pragma unroll
  for (int j = 0; j < 8; j++) onesv[j] = (short)0x3F80;  // bf16 1.0

  f32x16 o0 = {}, o1 = {}, lac = {};
  float m = -1e30f;

  STAGE_K(0, kb0 * 64);
  STAGE_V(0, kb0 * 64);
  STAGE_K(1, (kb0 + 1) * 64);
  STAGE_V(1, (kb0 + 1) * 64);
  BAR_VM4();   // tile kb0 landed; kb0+1 in flight

  for (int kb = kb0; kb <= kbmax; kb++) {
    const int idx = kb - kb0;
    const int cur = idx % 3, nxt = (idx + 2) % 3;
    const int pre = (kb + 2 <= kbmax);
    const int kbase = kb * 64;
    const int active = (kbase <= q0w + 31);      // wave has unmasked work
    const bfu* KsC = Ks[cur];
    const bfu* VsC = Vs[cur];
    // ---- phase 1: stage K(kb+2) early, then QK^T + softmax ----
    if (pre) STAGE_K(nxt, (kb + 2) * 64);
    u32 W0[8], W1[8];
    if (active) {
      f32x16 s0 = {}, s1 = {};
#pragma unroll
      for (int c = 0; c < 4; c++) {
        const int g = 2 * c + hi;
        bf16x8 kf0 = *(const bf16x8*)&KsC[(q31 * 8 + (g ^ (q31 & 7))) * 8];
        bf16x8 kf1 = *(const bf16x8*)&KsC[((32 + q31) * 8 + (g ^ (q31 & 7))) * 8];
        s0 = __builtin_amdgcn_mfma_f32_32x32x16_bf16(kf0, qv[c], s0, 0, 0, 0);
        s1 = __builtin_amdgcn_mfma_f32_32x32x16_bf16(kf1, qv[c], s1, 0, 0, 0);
      }
      if (kbase + 63 > q0w) {  // tile crosses diagonal: causal mask
#pragma unroll
        for (int r = 0; r < 16; r++) {
          int krow = (r & 3) + 8 * (r >> 2) + 4 * hi;
          if (kbase + krow > qg)      s0[r] = -1e30f;
          if (kbase + 32 + krow > qg) s1[r] = -1e30f;
        }
      }
      float pm = s0[0];
#pragma unroll
      for (int r = 1; r < 16; r++) pm = fmaxf(pm, s0[r]);
#pragma unroll
      for (int r = 0; r < 16; r++) pm = fmaxf(pm, s1[r]);
      pm = fmaxf(pm, __shfl_xor(pm, 32));
      if (!__all(pm <= m + 8.0f)) {
        float mn = fmaxf(m, pm);
        float al = __builtin_amdgcn_exp2f(m - mn);
        m = mn;
#pragma unroll
        for (int r = 0; r < 16; r++) {
          float alq = __shfl(al, (r & 3) + 8 * (r >> 2) + 4 * hi);
          o0[r] *= alq; o1[r] *= alq; lac[r] *= alq;
        }
      }
#pragma unroll
      for (int w = 0; w < 8; w++) {
        float a0 = __builtin_amdgcn_exp2f(s0[2 * w] - m);
        float a1 = __builtin_amdgcn_exp2f(s0[2 * w + 1] - m);
        asm("v_cvt_pk_bf16_f32 %0, %1, %2" : "=v"(W0[w]) : "v"(a0), "v"(a1));
        float b0 = __builtin_amdgcn_exp2f(s1[2 * w] - m);
        float b1 = __builtin_amdgcn_exp2f(s1[2 * w + 1] - m);
        asm("v_cvt_pk_bf16_f32 %0, %1, %2" : "=v"(W1[w]) : "v"(b0), "v"(b1));
      }
    }
    // ---- phase 2: stage V(kb+2) early, then PV + l ----
    if (pre) STAGE_V(nxt, (kb + 2) * 64);
    if (active) {
      __builtin_amdgcn_s_setprio(1);
#pragma unroll
      for (int c = 0; c < 4; c++) {
        const u32* Wsel = (c < 2) ? W0 : W1;
        const int w0 = 4 * (c & 1);
        u32 t0 = Wsel[w0],     t2 = Wsel[w0 + 2];
        u32 t1 = Wsel[w0 + 1], t3 = Wsel[w0 + 3];
        asm("v_permlane32_swap_b32 %0, %1" : "+v"(t0), "+v"(t2));
        asm("v_permlane32_swap_b32 %0, %1" : "+v"(t1), "+v"(t3));
        union { u32 u[4]; bf16x8 v; } pa;
        pa.u[0] = t0; pa.u[1] = t1; pa.u[2] = t2; pa.u[3] = t3;
        const int g = 2 * c + hi;
        bf16x8 vb0 = *(const bf16x8*)&VsC[(q31 * 8 + (g ^ (q31 & 7))) * 8];
        bf16x8 vb1 = *(const bf16x8*)&VsC[((32 + q31) * 8 + (g ^ (q31 & 7))) * 8];
        o0  = __builtin_amdgcn_mfma_f32_32x32x16_bf16(pa.v, vb0,   o0,  0, 0, 0);
        o1  = __builtin_amdgcn_mfma_f32_32x32x16_bf16(pa.v, vb1,   o1,  0, 0, 0);
        lac = __builtin_amdgcn_mfma_f32_32x32x16_bf16(pa.v, onesv, lac, 0, 0, 0);
      }
      __builtin_amdgcn_s_setprio(0);
    }
    // barrier: tile kb+1 landed (FIFO), tile kb+2's 4 loads stay in flight.
    if (pre) BAR_VM4();
    else     BAR_VM0();   // tail: drain remaining stages
  }
#undef STAGE_K
#undef STAGE_V

  if (mode == 0) {
    // direct epilogue: Ob[b*2048+t][h*64+d]
#pragma unroll
    for (int r = 0; r < 16; r++) {
      int t = q0w + (r & 3) + 8 * (r >> 2) + 4 * hi;
      float inv = 1.0f / lac[r];
      size_t base = (size_t)(b * 2048 + t) * 1024 + h * 64;
      Ob[base + q31]      = f2bf(o0[r] * inv);
      Ob[base + 32 + q31] = f2bf(o1[r] * inv);
    }
  } else {
    // partial epilogue: p in [0,768); o as bf16 [128][64], m/l fp32 [128]
    const int p = (hb * 12 + (qb - 4)) * 2 + (mode - 1);
    bfu*   po = PO + (size_t)p * 8192;
    float* pmv = PM + p * 128;
    float* plv = PL + p * 128;
    pmv[wave * 32 + q31] = m;
#pragma unroll
    for (int r = 0; r < 16; r++) {
      int rm = (r & 3) + 8 * (r >> 2) + 4 * hi;
      plv[wave * 32 + rm] = lac[r];
      po[(wave * 32 + rm) * 64 + q31]      = f2bf(o0[r]);
      po[(wave * 32 + rm) * 64 + 32 + q31] = f2bf(o1[r]);
    }
  }
}

// combine the two equal halves for qb>=4: 384 WGs = (hb, qb-4).
__global__ __launch_bounds__(256) void attn_comb(
    const bfu* __restrict__ PO, const float* __restrict__ PM,
    const float* __restrict__ PL, bfu* __restrict__ Ob) {
  const int g = blockIdx.x;            // 0..383
  const int hb = g / 12, j = g % 12, qb = j + 4;
  const int b = hb >> 4, h = hb & 15;
  const int p0 = g * 2, p1 = p0 + 1;
  const int tid = threadIdx.x;
  const int r = tid >> 1, ch = tid & 1;          // row 0..127, col-half
  float m0 = PM[p0 * 128 + r], m1 = PM[p1 * 128 + r];
  float l0 = PL[p0 * 128 + r], l1 = PL[p1 * 128 + r];
  float ms = fmaxf(m0, m1);
  float f0 = __builtin_amdgcn_exp2f(m0 - ms);
  float f1 = __builtin_amdgcn_exp2f(m1 - ms);
  float inv = 1.0f / (l0 * f0 + l1 * f1);
  const bfu* a0 = PO + (size_t)p0 * 8192 + r * 64 + ch * 32;
  const bfu* a1 = PO + (size_t)p1 * 8192 + r * 64 + ch * 32;
  const int t = qb * 128 + r;
  bfu* ob = Ob + (size_t)(b * 2048 + t) * 1024 + h * 64 + ch * 32;
#pragma unroll
  for (int k = 0; k < 4; k++) {
    bf16x8 v0 = *(const bf16x8*)(a0 + k * 8);
    bf16x8 v1 = *(const bf16x8*)(a1 + k * 8);
    bf16x8 vo;
#pragma unroll
    for (int e = 0; e < 8; e++) {
      float acc = bf2f((bfu)(unsigned short)v0[e]) * f0 +
                  bf2f((bfu)(unsigned short)v1[e]) * f1;
      vo[e] = (short)f2bf(acc * inv);
    }
    *(bf16x8*)(ob + k * 8) = vo;
  }
}

// ---------------- launch ----------------

extern "C" void kernel_launch(void* const* d_in, const int* in_sizes, int n_in,
                              void* d_out, int out_size, void* d_ws, size_t ws_size,
                              hipStream_t stream) {
  const float* x  = (const float*)d_in[0];
  const float* Wk = (const float*)d_in[1];  // note dict order: Wk before Wq!
  const float* Wq = (const float*)d_in[2];
  const float* Wv = (const float*)d_in[3];
  const float* Wp = (const float*)d_in[4];
  const float* bp = (const float*)d_in[5];
  char* ws = (char*)d_ws;
  bfu* xb  = (bfu*)(ws);
  bfu* Wqt = (bfu*)(ws + ( 8u << 20));   // start of contiguous [3072][1024] B^T
  bfu* Wkt = (bfu*)(ws + (10u << 20));
  bfu* Wvt = (bfu*)(ws + (12u << 20));
  bfu* Wpt = (bfu*)(ws + (14u << 20));
  bfu* Qb  = (bfu*)(ws + (16u << 20));
  bfu* Kb  = (bfu*)(ws + (24u << 20));
  bfu* Vb  = (bfu*)(ws + (32u << 20));
  bfu* Ab  = (bfu*)(ws + (40u << 20));
  bfu*   PO = (bfu*)(ws);                         // 768 x 8192 bf16 = 12.6 MB
  float* PM = (float*)(ws + (13u << 20));         // 768 x 128 fp32
  float* PL = (float*)(ws + (13u << 20) + (512u << 10));  // +0.5 MB
  float* out = (float*)d_out;

  conv_x<<<1024, 256, 0, stream>>>(x, xb);
  conv_w<<<dim3(16, 16, 4), 256, 0, stream>>>(Wq, Wk, Wv, Wp, Wqt, Wkt, Wvt, Wpt);
  gemm_qkv192<<<256, 512, 0, stream>>>(xb, Wqt, Qb, Kb, Vb);
  attn_fwd<<<1024, 256, 0, stream>>>(Qb, Kb, Vb, Ab, PO, PM, PL);
  attn_comb<<<384, 256, 0, stream>>>(PO, PM, PL, Ab);
  gemm_proj<<<256, 512, 0, stream>>>(Ab, Wpt, bp, out);
}

// Round 19
// 109.565 us; speedup vs baseline: 1.0421x; 1.0171x over previous
//
#include <hip/hip_runtime.h>
#include <stdint.h>

// MultiHeadAttention fused pipeline for MI355X (gfx950).
// B=2, T=2048, C=1024, H=16, Dh=64. All inputs fp32; compute in bf16 MFMA.
//
// ws layout (48 MiB):
//   [ 0MB) xb   : x as bf16 [4096][1024]     -- after attn: partial-O (bf16, 12.6MB)
//   [ 8MB) Wqt  : Wq^T bf16  \
//   [10MB) Wkt              -- contiguous [3072][1024] B^T for the fused QKV GEMM
//   [12MB) Wvt              /
//   [13MB) PM (fp32 768x128), [13.5MB) PL (fp32 768x128)   -- attn partials m/l
//   [14MB) Wpt  (LIVE until gemm_proj -- partials must stay below 14MB)
//   [16MB) Qb   : [32 head][2048 t][64 d] bf16  (PRE-SCALED by 0.125*log2e)
//   [24MB) Kb   : same layout (unscaled)
//   [32MB) Vb   : TRANSPOSED [32 head][64 d][2048 t] bf16
//   [40MB) Ab   : attention out [4096][1024] bf16

typedef unsigned short bfu;                               // bf16 bits
typedef unsigned int u32;
typedef short bf16x8 __attribute__((ext_vector_type(8))); // 8 bf16 (4 VGPRs)
typedef float f32x4 __attribute__((ext_vector_type(4)));
typedef float f32x16 __attribute__((ext_vector_type(16)));

#define DEVI static __device__ __forceinline__

DEVI bfu f2bf(float f) {  // round-to-nearest-even fp32 -> bf16 bits
  union { float f; unsigned u; } a; a.f = f;
  unsigned u = a.u;
  u += 0x7fffu + ((u >> 16) & 1u);
  return (bfu)(u >> 16);
}

DEVI float bf2f(bfu x) {
  union { u32 u; float f; } a; a.u = ((u32)x) << 16; return a.f;
}

DEVI void gld_lds16(const void* g, void* l) {
  __builtin_amdgcn_global_load_lds(
      (const __attribute__((address_space(1))) void*)g,
      (__attribute__((address_space(3))) void*)l, 16, 0, 0);
}

#define BAR_VMN(N)                                        \
  do {                                                    \
    asm volatile("s_waitcnt vmcnt(" #N ")" ::: "memory"); \
    __builtin_amdgcn_s_barrier();                         \
    asm volatile("" ::: "memory");                        \
  } while (0)
#define BAR_VM5() BAR_VMN(5)
#define BAR_VM4() BAR_VMN(4)
#define BAR_VM2() BAR_VMN(2)
#define BAR_VM0() BAR_VMN(0)

// ------------- merged prep: conv_x (blocks 0..1023) + conv_w (1024..2047) -------------

__global__ __launch_bounds__(256) void prep(
    const float* __restrict__ x, bfu* __restrict__ xb,
    const float* __restrict__ W0, const float* __restrict__ W1,
    const float* __restrict__ W2, const float* __restrict__ W3,
    bfu* __restrict__ T0, bfu* __restrict__ T1,
    bfu* __restrict__ T2, bfu* __restrict__ T3) {
  __shared__ bfu tile[64][65];
  if (blockIdx.x < 1024) {
    // conv_x: fp32 -> bf16, vectorized
    const int n4 = (4096 * 1024) / 4;
    for (int i = blockIdx.x * 256 + threadIdx.x; i < n4; i += 1024 * 256) {
      float4 v = ((const float4*)x)[i];
      ushort4 p;
      p.x = f2bf(v.x); p.y = f2bf(v.y); p.z = f2bf(v.z); p.w = f2bf(v.w);
      ((ushort4*)xb)[i] = p;
    }
  } else {
    // conv_w: convert + transpose a 1024x1024 fp32 [k][n] -> bf16 [n][k]
    const int j = blockIdx.x - 1024;
    const int z = j >> 8, by = (j >> 4) & 15, bx = j & 15;
    const float* W; bfu* T;
    switch (z) {
      case 0:  W = W0; T = T0; break;
      case 1:  W = W1; T = T1; break;
      case 2:  W = W2; T = T2; break;
      default: W = W3; T = T3; break;
    }
    const int k0 = by * 64, n0 = bx * 64;
    const int c = threadIdx.x & 63, r4 = threadIdx.x >> 6;
#pragma unroll
    for (int i = 0; i < 16; i++) {
      int row = r4 + i * 4;  // k-local
      tile[row][c] = f2bf(W[(size_t)(k0 + row) * 1024 + n0 + c]);
    }
    __syncthreads();
#pragma unroll
    for (int i = 0; i < 16; i++) {
      int row = r4 + i * 4;  // n-local
      T[(size_t)(n0 + row) * 1024 + k0 + c] = tile[c][row];
    }
  }
}

// ======== fused QKV GEMM v2: 256x192 tile, grid 256 (1 WG/CU), 8-wave ========
// (r18 bench-proven source, unchanged)

__global__ __launch_bounds__(512) void gemm_qkv192(
    const bfu* __restrict__ A, const bfu* __restrict__ Bt,
    bfu* __restrict__ Qb, bfu* __restrict__ Kb, bfu* __restrict__ Vb) {
  __shared__ __align__(16) bfu LDS[2 * 28672];   // 112 KB
  const int bid = blockIdx.x;
  const int xcd = bid & 7, i0 = bid >> 3;        // i0 0..31
  const int ty = xcd * 2 + (i0 & 1), tx = i0 >> 1;   // ty 0..15, tx 0..15
  const int m0 = ty * 256, n0g = tx * 192;
  const int tid = threadIdx.x, wave = tid >> 6, lane = tid & 63;
  const int wr = wave >> 2, wc = wave & 3;       // wave grid 2M x 4N (128x48/wave)
  const int fr = lane & 15, fq = lane >> 4;
  const int rslot4 = fq ^ ((fr >> 1) & 3);       // T2 read-side swizzle

#define STAGE_A(bufn, ktile, kk)                                                 \
  do {                                                                           \
    _Pragma("unroll")                                                            \
    for (int j_ = 0; j_ < 2; j_++) {                                             \
      int s_ = tid + j_ * 512;                                                   \
      int r_ = s_ >> 2, cg_ = (s_ & 3) ^ ((r_ >> 1) & 3);                        \
      gld_lds16(A + (size_t)(m0 + r_) * 1024 + (ktile) * 64 + (kk) * 32 + cg_ * 8,\
                LDS + (bufn) * 28672 + (kk) * 8192 + s_ * 8);                    \
    }                                                                            \
  } while (0)
#define STAGE_B(bufn, ktile)                                                     \
  do {                                                                           \
    _Pragma("unroll")                                                            \
    for (int j_ = 0; j_ < 3; j_++) {                                             \
      int s_ = tid + j_ * 512;                                                   \
      int kk_ = (s_ >= 768) ? 1 : 0;                                             \
      int sp_ = s_ - kk_ * 768;                                                  \
      int r_ = sp_ >> 2, cg_ = (sp_ & 3) ^ ((r_ >> 1) & 3);                      \
      gld_lds16(Bt + (size_t)(n0g + r_) * 1024 + (ktile) * 64 + kk_ * 32 + cg_ * 8,\
                LDS + (bufn) * 28672 + 16384 + s_ * 8);                          \
    }                                                                            \
  } while (0)

#define READ_B(kk)                                                               \
  _Pragma("unroll")                                                              \
  for (int n = 0; n < 3; n++)                                                    \
    bfv[n] = *(const bf16x8*)&bufc_p[16384 + (kk) * 6144 +                       \
              ((wc * 48 + n * 16 + fr) * 4 + rslot4) * 8];

#define READ_A(dst, mq, kk)                                                      \
  _Pragma("unroll")                                                              \
  for (int mm = 0; mm < 4; mm++)                                                 \
    dst[mm] = *(const bf16x8*)&bufc_p[(kk) * 8192 +                              \
              ((wr * 128 + ((mq) * 4 + mm) * 16 + fr) * 4 + rslot4) * 8];

#define MFMA_Q(afv, mq)                                                          \
  __builtin_amdgcn_s_setprio(1);                                                 \
  _Pragma("unroll")                                                              \
  for (int mm = 0; mm < 4; mm++)                                                 \
    _Pragma("unroll")                                                            \
    for (int n = 0; n < 3; n++)                                                  \
      acc[(mq) * 4 + mm][n] = __builtin_amdgcn_mfma_f32_16x16x32_bf16(           \
          afv[mm], bfv[n], acc[(mq) * 4 + mm][n], 0, 0, 0);                      \
  __builtin_amdgcn_s_setprio(0);

  f32x4 acc[8][3] = {};
  STAGE_A(0, 0, 0);
  STAGE_B(0, 0);
  STAGE_A(0, 0, 1);
  BAR_VM2();

  const int NT = 16;      // K=1024 / BK=64
  for (int t = 0; t < NT; t++) {
    const int more = (t + 1 < NT);
    const bfu* bufc_p = LDS + (t & 1) * 28672;
    const int bufn = (t & 1) ^ 1;
    bf16x8 bfv[3], afA[4], afB[4];
    // ---- k-half 0 ----
    READ_B(0);
    READ_A(afA, 0, 0);
    if (more) STAGE_A(bufn, t + 1, 0);   // 2 loads
    MFMA_Q(afA, 0);
    READ_A(afB, 1, 0);
    if (more) STAGE_B(bufn, t + 1);      // 3 loads
    MFMA_Q(afB, 1);
    if (more) BAR_VM5();    // A_k1(t) landed; A_k0(t+1)+B(t+1) in flight
    else      BAR_VM0();    // last tile: drain own A_k1
    // ---- k-half 1 ----
    READ_B(1);
    READ_A(afA, 0, 1);
    if (more) STAGE_A(bufn, t + 1, 1);   // 2 loads
    MFMA_Q(afA, 0);
    READ_A(afB, 1, 1);
    MFMA_Q(afB, 1);
    if (more) BAR_VM2();    // A_k0(t+1)+B(t+1) landed; A_k1(t+1) in flight
    else      BAR_VM0();
  }
#undef STAGE_A
#undef STAGE_B
#undef READ_B
#undef READ_A
#undef MFMA_Q

  // epilogue: per-element Q|K|V straddle (col C in [0,3072))
  const float qs = 0.1803368801f;  // 0.125*log2e (Q only)
#pragma unroll
  for (int mf = 0; mf < 8; mf++)
#pragma unroll
    for (int n = 0; n < 3; n++) {
      int r = m0 + wr * 128 + mf * 16 + fq * 4;      // global row
      int C = n0g + wc * 48 + n * 16 + fr;           // global col 0..3071
      int z = C >> 10, cwm = C & 1023;
      int b = r >> 11, tt = r & 2047, h = cwm >> 6, d = cwm & 63;
      if (z == 0) {
        size_t base = ((size_t)(b * 16 + h) * 2048 + tt) * 64 + d;
#pragma unroll
        for (int i = 0; i < 4; i++)
          Qb[base + (size_t)i * 64] = f2bf(acc[mf][n][i] * qs);
      } else if (z == 1) {
        size_t base = ((size_t)(b * 16 + h) * 2048 + tt) * 64 + d;
#pragma unroll
        for (int i = 0; i < 4; i++)
          Kb[base + (size_t)i * 64] = f2bf(acc[mf][n][i]);
      } else {
        size_t base = ((size_t)(b * 16 + h) * 64 + d) * 2048 + tt;
        ushort4 p;
        p.x = f2bf(acc[mf][n][0]); p.y = f2bf(acc[mf][n][1]);
        p.z = f2bf(acc[mf][n][2]); p.w = f2bf(acc[mf][n][3]);
        *(ushort4*)&Vb[base] = p;
      }
    }
}

// ======== output projection v2: 128^2 tile, 8-wave, 4-phase/K-tile ========
// (r16 bench-proven source, unchanged)

__global__ __launch_bounds__(512) void gemm_proj(
    const bfu* __restrict__ A, const bfu* __restrict__ Bt,
    const float* __restrict__ bias, float* __restrict__ out) {
  __shared__ __align__(16) bfu LDS[2 * 16384];   // 64 KB
  const int bid = blockIdx.x;
  const int xcd = bid & 7, i0 = bid >> 3;        // i0 0..31
  const int tx = i0 >> 2, ty = xcd * 4 + (i0 & 3);   // tx 0..7, ty 0..31
  const int m0 = ty * 128, n0 = tx * 128;
  const int tid = threadIdx.x, wave = tid >> 6, lane = tid & 63;
  const int wr = wave >> 1, wc = wave & 1;       // wave grid 4M x 2N
  const int fr = lane & 15, fq = lane >> 4;
  const int rslot4 = fq ^ ((fr >> 1) & 3);       // T2 read-side swizzle

#define STAGE_HT(bufn, ktile, isB, kk)                                           \
  do {                                                                           \
    const bfu* srcb = (isB) ? Bt + (size_t)n0 * 1024 : A + (size_t)m0 * 1024;    \
    bfu* dstb = LDS + (bufn) * 16384 + ((isB) ? 8192 : 0) + (kk) * 4096;         \
    int r_ = tid >> 2, cg_ = (tid & 3) ^ ((r_ >> 1) & 3);                        \
    gld_lds16(srcb + (size_t)r_ * 1024 + (ktile) * 64 + (kk) * 32 + cg_ * 8,     \
              dstb + tid * 8);                                                   \
  } while (0)

#define READ_B(kk)                                                               \
  _Pragma("unroll")                                                              \
  for (int n = 0; n < 4; n++)                                                    \
    bfv[n] = *(const bf16x8*)&bufc_p[8192 + (kk) * 4096 +                        \
              ((wc * 64 + n * 16 + fr) * 4 + rslot4) * 8];

#define READ_A(kk)                                                               \
  _Pragma("unroll")                                                              \
  for (int mm = 0; mm < 2; mm++)                                                 \
    af[mm] = *(const bf16x8*)&bufc_p[(kk) * 4096 +                               \
              ((wr * 32 + mm * 16 + fr) * 4 + rslot4) * 8];

#define MFMA_H(nq)                                                               \
  __builtin_amdgcn_s_setprio(1);                                                 \
  _Pragma("unroll")                                                              \
  for (int mm = 0; mm < 2; mm++)                                                 \
    _Pragma("unroll")                                                            \
    for (int n = 0; n < 2; n++)                                                  \
      acc[mm][(nq) * 2 + n] = __builtin_amdgcn_mfma_f32_16x16x32_bf16(           \
          af[mm], bfv[(nq) * 2 + n], acc[mm][(nq) * 2 + n], 0, 0, 0);            \
  __builtin_amdgcn_s_setprio(0);

  f32x4 acc[2][4] = {};
  STAGE_HT(0, 0, 0, 0);   // A_k0
  STAGE_HT(0, 0, 1, 0);   // B_k0
  STAGE_HT(0, 0, 0, 1);   // A_k1
  STAGE_HT(0, 0, 1, 1);   // B_k1
  BAR_VM2();              // A_k0,B_k0 landed; A_k1,B_k1 in flight

  const int NT = 16;      // K=1024 / BK=64
  for (int t = 0; t < NT; t++) {
    const int more = (t + 1 < NT);
    const bfu* bufc_p = LDS + (t & 1) * 16384;
    const int bufn = (t & 1) ^ 1;
    bf16x8 bfv[4], af[2];
    // ---- k-half 0 ----
    READ_B(0);
    READ_A(0);
    if (more) STAGE_HT(bufn, t + 1, 0, 0);   // A_k0(t+1)
    MFMA_H(0);
    if (more) STAGE_HT(bufn, t + 1, 1, 0);   // B_k0(t+1)
    MFMA_H(1);
    if (more) BAR_VM2();    // A_k1,B_k1(t) landed; k0(t+1) in flight
    else      BAR_VM0();    // last tile: drain own k1 halves
    // ---- k-half 1 ----
    READ_B(1);
    READ_A(1);
    if (more) STAGE_HT(bufn, t + 1, 0, 1);   // A_k1(t+1)
    MFMA_H(0);
    if (more) STAGE_HT(bufn, t + 1, 1, 1);   // B_k1(t+1)
    MFMA_H(1);
    BAR_VM2();              // A_k0,B_k0(t+1) landed; k1(t+1) in flight
  }
#undef STAGE_HT
#undef READ_B
#undef READ_A
#undef MFMA_H

  // epilogue: fp32 + bias
#pragma unroll
  for (int mm = 0; mm < 2; mm++)
#pragma unroll
    for (int n = 0; n < 4; n++) {
      int r = m0 + wr * 32 + mm * 16 + fq * 4;
      int c = n0 + wc * 64 + n * 16 + fr;
      float bv = bias[c];
#pragma unroll
      for (int i = 0; i < 4; i++)
        out[(size_t)(r + i) * 1024 + c] = acc[mm][n][i] + bv;
    }
}

// ---- flash attention (causal) v11: split-K schedule + TRIPLE-buffer counted
// vmcnt with per-phase stage interleave (r16 bench-proven source, unchanged).

__global__ __launch_bounds__(256) void attn_fwd(
    const bfu* __restrict__ Q, const bfu* __restrict__ K,
    const bfu* __restrict__ Vt, bfu* __restrict__ Ob,
    bfu* __restrict__ PO, float* __restrict__ PM, float* __restrict__ PL) {
  __shared__ __align__(16) bfu Ks[3][4096];   // 8 KB each buf (64 keys x 64 d)
  __shared__ __align__(16) bfu Vs[3][4096];
  const int bid = blockIdx.x;
  const int xcd = bid & 7, i0 = bid >> 3;        // i0 0..127
  const int slot = i0 >> 5, cuL = i0 & 31;       // slot = dispatch pass
  const int head = cuL >> 3, cu8 = cuL & 7;
  const int hb = xcd * 4 + head;                 // head instance (= b*16+h)
  int qb, mode;                                  // mode 0=full,1=half0,2=half1
  if (slot < 2)      { qb = 15 - cu8; mode = slot + 1; }
  else if (cu8 < 4)  { if (slot == 3) return; qb = cu8; mode = 0; }
  else               { qb = cu8; mode = slot - 1; }
  const int kb0   = (mode == 2) ? (qb + 1) : 0;
  const int kbmax = (mode == 1) ? qb : (2 * qb + 1);
  const int tid = threadIdx.x, wave = tid >> 6, lane = tid & 63;
  const int q31 = lane & 31, hi = lane >> 5;
  const bfu* Qh = Q  + (size_t)hb * 2048 * 64;
  const bfu* Kh = K  + (size_t)hb * 2048 * 64;
  const bfu* Vh = Vt + (size_t)hb * 64 * 2048;
  const int b = hb >> 4, h = hb & 15;
  const int q0w = qb * 128 + wave * 32;          // this wave's 32 q rows
  const int qg = q0w + q31;

  const int r0 = tid >> 3, r1 = (256 + tid) >> 3;
  const int c0 = (tid & 7) ^ (r0 & 7), c1 = (tid & 7) ^ (r1 & 7);
#define STAGE_K(bufi, kbase)                                                          \
  do {                                                                                \
    gld_lds16(Kh + (size_t)((kbase) + r0) * 64 + c0 * 8, &Ks[bufi][tid * 8]);         \
    gld_lds16(Kh + (size_t)((kbase) + r1) * 64 + c1 * 8, &Ks[bufi][(256 + tid) * 8]); \
  } while (0)
#define STAGE_V(bufi, kbase)                                                          \
  do {                                                                                \
    gld_lds16(Vh + (size_t)r0 * 2048 + (kbase) + c0 * 8, &Vs[bufi][tid * 8]);         \
    gld_lds16(Vh + (size_t)r1 * 2048 + (kbase) + c1 * 8, &Vs[bufi][(256 + tid) * 8]); \
  } while (0)

  bf16x8 qv[4];
#pragma unroll
  for (int c = 0; c < 4; c++)
    qv[c] = *(const bf16x8*)&Qh[(size_t)(q0w + q31) * 64 + c * 16 + hi * 8];

  bf16x8 onesv;
#pragma unroll
  for (int j = 0; j < 8; j++) onesv[j] = (short)0x3F80;  // bf16 1.0

  f32x16 o0 = {}, o1 = {}, lac = {};
  float m = -1e30f;

  STAGE_K(0, kb0 * 64);
  STAGE_V(0, kb0 * 64);
  STAGE_K(1, (kb0 + 1) * 64);
  STAGE_V(1, (kb0 + 1) * 64);
  BAR_VM4();   // tile kb0 landed; kb0+1 in flight

  for (int kb = kb0; kb <= kbmax; kb++) {
    const int idx = kb - kb0;
    const int cur = idx % 3, nxt = (idx + 2) % 3;
    const int pre = (kb + 2 <= kbmax);
    const int kbase = kb * 64;
    const int active = (kbase <= q0w + 31);      // wave has unmasked work
    const bfu* KsC = Ks[cur];
    const bfu* VsC = Vs[cur];
    // ---- phase 1: stage K(kb+2) early, then QK^T + softmax ----
    if (pre) STAGE_K(nxt, (kb + 2) * 64);
    u32 W0[8], W1[8];
    if (active) {
      f32x16 s0 = {}, s1 = {};
#pragma unroll
      for (int c = 0; c < 4; c++) {
        const int g = 2 * c + hi;
        bf16x8 kf0 = *(const bf16x8*)&KsC[(q31 * 8 + (g ^ (q31 & 7))) * 8];
        bf16x8 kf1 = *(const bf16x8*)&KsC[((32 + q31) * 8 + (g ^ (q31 & 7))) * 8];
        s0 = __builtin_amdgcn_mfma_f32_32x32x16_bf16(kf0, qv[c], s0, 0, 0, 0);
        s1 = __builtin_amdgcn_mfma_f32_32x32x16_bf16(kf1, qv[c], s1, 0, 0, 0);
      }
      if (kbase + 63 > q0w) {  // tile crosses diagonal: causal mask
#pragma unroll
        for (int r = 0; r < 16; r++) {
          int krow = (r & 3) + 8 * (r >> 2) + 4 * hi;
          if (kbase + krow > qg)      s0[r] = -1e30f;
          if (kbase + 32 + krow > qg) s1[r] = -1e30f;
        }
      }
      float pm = s0[0];
#pragma unroll
      for (int r = 1; r < 16; r++) pm = fmaxf(pm, s0[r]);
#pragma unroll
      for (int r = 0; r < 16; r++) pm = fmaxf(pm, s1[r]);
      pm = fmaxf(pm, __shfl_xor(pm, 32));
      if (!__all(pm <= m + 8.0f)) {
        float mn = fmaxf(m, pm);
        float al = __builtin_amdgcn_exp2f(m - mn);
        m = mn;
#pragma unroll
        for (int r = 0; r < 16; r++) {
          float alq = __shfl(al, (r & 3) + 8 * (r >> 2) + 4 * hi);
          o0[r] *= alq; o1[r] *= alq; lac[r] *= alq;
        }
      }
#pragma unroll
      for (int w = 0; w < 8; w++) {
        float a0 = __builtin_amdgcn_exp2f(s0[2 * w] - m);
        float a1 = __builtin_amdgcn_exp2f(s0[2 * w + 1] - m);
        asm("v_cvt_pk_bf16_f32 %0, %1, %2" : "=v"(W0[w]) : "v"(a0), "v"(a1));
        float b0 = __builtin_amdgcn_exp2f(s1[2 * w] - m);
        float b1 = __builtin_amdgcn_exp2f(s1[2 * w + 1] - m);
        asm("v_cvt_pk_bf16_f32 %0, %1, %2" : "=v"(W1[w]) : "v"(b0), "v"(b1));
      }
    }
    // ---- phase 2: stage V(kb+2) early, then PV + l ----
    if (pre) STAGE_V(nxt, (kb + 2) * 64);
    if (active) {
      __builtin_amdgcn_s_setprio(1);
#pragma unroll
      for (int c = 0; c < 4; c++) {
        const u32* Wsel = (c < 2) ? W0 : W1;
        const int w0 = 4 * (c & 1);
        u32 t0 = Wsel[w0],     t2 = Wsel[w0 + 2];
        u32 t1 = Wsel[w0 + 1], t3 = Wsel[w0 + 3];
        asm("v_permlane32_swap_b32 %0, %1" : "+v"(t0), "+v"(t2));
        asm("v_permlane32_swap_b32 %0, %1" : "+v"(t1), "+v"(t3));
        union { u32 u[4]; bf16x8 v; } pa;
        pa.u[0] = t0; pa.u[1] = t1; pa.u[2] = t2; pa.u[3] = t3;
        const int g = 2 * c + hi;
        bf16x8 vb0 = *(const bf16x8*)&VsC[(q31 * 8 + (g ^ (q31 & 7))) * 8];
        bf16x8 vb1 = *(const bf16x8*)&VsC[((32 + q31) * 8 + (g ^ (q31 & 7))) * 8];
        o0  = __builtin_amdgcn_mfma_f32_32x32x16_bf16(pa.v, vb0,   o0,  0, 0, 0);
        o1  = __builtin_amdgcn_mfma_f32_32x32x16_bf16(pa.v, vb1,   o1,  0, 0, 0);
        lac = __builtin_amdgcn_mfma_f32_32x32x16_bf16(pa.v, onesv, lac, 0, 0, 0);
      }
      __builtin_amdgcn_s_setprio(0);
    }
    // barrier: tile kb+1 landed (FIFO), tile kb+2's 4 loads stay in flight.
    if (pre) BAR_VM4();
    else     BAR_VM0();   // tail: drain remaining stages
  }
#undef STAGE_K
#undef STAGE_V

  if (mode == 0) {
    // direct epilogue: Ob[b*2048+t][h*64+d]
#pragma unroll
    for (int r = 0; r < 16; r++) {
      int t = q0w + (r & 3) + 8 * (r >> 2) + 4 * hi;
      float inv = 1.0f / lac[r];
      size_t base = (size_t)(b * 2048 + t) * 1024 + h * 64;
      Ob[base + q31]      = f2bf(o0[r] * inv);
      Ob[base + 32 + q31] = f2bf(o1[r] * inv);
    }
  } else {
    // partial epilogue: p in [0,768); o as bf16 [128][64], m/l fp32 [128]
    const int p = (hb * 12 + (qb - 4)) * 2 + (mode - 1);
    bfu*   po = PO + (size_t)p * 8192;
    float* pmv = PM + p * 128;
    float* plv = PL + p * 128;
    pmv[wave * 32 + q31] = m;
#pragma unroll
    for (int r = 0; r < 16; r++) {
      int rm = (r & 3) + 8 * (r >> 2) + 4 * hi;
      plv[wave * 32 + rm] = lac[r];
      po[(wave * 32 + rm) * 64 + q31]      = f2bf(o0[r]);
      po[(wave * 32 + rm) * 64 + 32 + q31] = f2bf(o1[r]);
    }
  }
}

// combine the two equal halves for qb>=4: 384 WGs = (hb, qb-4).
__global__ __launch_bounds__(256) void attn_comb(
    const bfu* __restrict__ PO, const float* __restrict__ PM,
    const float* __restrict__ PL, bfu* __restrict__ Ob) {
  const int g = blockIdx.x;            // 0..383
  const int hb = g / 12, j = g % 12, qb = j + 4;
  const int b = hb >> 4, h = hb & 15;
  const int p0 = g * 2, p1 = p0 + 1;
  const int tid = threadIdx.x;
  const int r = tid >> 1, ch = tid & 1;          // row 0..127, col-half
  float m0 = PM[p0 * 128 + r], m1 = PM[p1 * 128 + r];
  float l0 = PL[p0 * 128 + r], l1 = PL[p1 * 128 + r];
  float ms = fmaxf(m0, m1);
  float f0 = __builtin_amdgcn_exp2f(m0 - ms);
  float f1 = __builtin_amdgcn_exp2f(m1 - ms);
  float inv = 1.0f / (l0 * f0 + l1 * f1);
  const bfu* a0 = PO + (size_t)p0 * 8192 + r * 64 + ch * 32;
  const bfu* a1 = PO + (size_t)p1 * 8192 + r * 64 + ch * 32;
  const int t = qb * 128 + r;
  bfu* ob = Ob + (size_t)(b * 2048 + t) * 1024 + h * 64 + ch * 32;
#pragma unroll
  for (int k = 0; k < 4; k++) {
    bf16x8 v0 = *(const bf16x8*)(a0 + k * 8);
    bf16x8 v1 = *(const bf16x8*)(a1 + k * 8);
    bf16x8 vo;
#pragma unroll
    for (int e = 0; e < 8; e++) {
      float acc = bf2f((bfu)(unsigned short)v0[e]) * f0 +
                  bf2f((bfu)(unsigned short)v1[e]) * f1;
      vo[e] = (short)f2bf(acc * inv);
    }
    *(bf16x8*)(ob + k * 8) = vo;
  }
}

// ---------------- launch ----------------

extern "C" void kernel_launch(void* const* d_in, const int* in_sizes, int n_in,
                              void* d_out, int out_size, void* d_ws, size_t ws_size,
                              hipStream_t stream) {
  const float* x  = (const float*)d_in[0];
  const float* Wk = (const float*)d_in[1];  // note dict order: Wk before Wq!
  const float* Wq = (const float*)d_in[2];
  const float* Wv = (const float*)d_in[3];
  const float* Wp = (const float*)d_in[4];
  const float* bp = (const float*)d_in[5];
  char* ws = (char*)d_ws;
  bfu* xb  = (bfu*)(ws);
  bfu* Wqt = (bfu*)(ws + ( 8u << 20));   // start of contiguous [3072][1024] B^T
  bfu* Wkt = (bfu*)(ws + (10u << 20));
  bfu* Wvt = (bfu*)(ws + (12u << 20));
  bfu* Wpt = (bfu*)(ws + (14u << 20));
  bfu* Qb  = (bfu*)(ws + (16u << 20));
  bfu* Kb  = (bfu*)(ws + (24u << 20));
  bfu* Vb  = (bfu*)(ws + (32u << 20));
  bfu* Ab  = (bfu*)(ws + (40u << 20));
  bfu*   PO = (bfu*)(ws);                         // 768 x 8192 bf16 = 12.6 MB
  float* PM = (float*)(ws + (13u << 20));         // 768 x 128 fp32
  float* PL = (float*)(ws + (13u << 20) + (512u << 10));  // +0.5 MB
  float* out = (float*)d_out;

  prep<<<2048, 256, 0, stream>>>(x, xb, Wq, Wk, Wv, Wp, Wqt, Wkt, Wvt, Wpt);
  gemm_qkv192<<<256, 512, 0, stream>>>(xb, Wqt, Qb, Kb, Vb);
  attn_fwd<<<1024, 256, 0, stream>>>(Qb, Kb, Vb, Ab, PO, PM, PL);
  attn_comb<<<384, 256, 0, stream>>>(PO, PM, PL, Ab);
  gemm_proj<<<256, 512, 0, stream>>>(Ab, Wpt, bp, out);
}

// Round 21
// 109.442 us; speedup vs baseline: 1.0433x; 1.0011x over previous
//
#include <hip/hip_runtime.h>
#include <stdint.h>

// MultiHeadAttention fused pipeline for MI355X (gfx950).
// B=2, T=2048, C=1024, H=16, Dh=64. All inputs fp32; compute in bf16 MFMA.
// (r19 bench-proven configuration: 109.6 us, absmax 0.015625)
//
// ws layout (48 MiB):
//   [ 0MB) xb   : x as bf16 [4096][1024]     -- after attn: partial-O (bf16, 12.6MB)
//   [ 8MB) Wqt  : Wq^T bf16  \
//   [10MB) Wkt              -- contiguous [3072][1024] B^T for the fused QKV GEMM
//   [12MB) Wvt              /
//   [13MB) PM (fp32 768x128), [13.5MB) PL (fp32 768x128)   -- attn partials m/l
//   [14MB) Wpt  (LIVE until gemm_proj -- partials must stay below 14MB)
//   [16MB) Qb   : [32 head][2048 t][64 d] bf16  (PRE-SCALED by 0.125*log2e)
//   [24MB) Kb   : same layout (unscaled)
//   [32MB) Vb   : TRANSPOSED [32 head][64 d][2048 t] bf16
//   [40MB) Ab   : attention out [4096][1024] bf16

typedef unsigned short bfu;                               // bf16 bits
typedef unsigned int u32;
typedef short bf16x8 __attribute__((ext_vector_type(8))); // 8 bf16 (4 VGPRs)
typedef float f32x4 __attribute__((ext_vector_type(4)));
typedef float f32x16 __attribute__((ext_vector_type(16)));

#define DEVI static __device__ __forceinline__

DEVI bfu f2bf(float f) {  // round-to-nearest-even fp32 -> bf16 bits
  union { float f; unsigned u; } a; a.f = f;
  unsigned u = a.u;
  u += 0x7fffu + ((u >> 16) & 1u);
  return (bfu)(u >> 16);
}

DEVI float bf2f(bfu x) {
  union { u32 u; float f; } a; a.u = ((u32)x) << 16; return a.f;
}

DEVI void gld_lds16(const void* g, void* l) {
  __builtin_amdgcn_global_load_lds(
      (const __attribute__((address_space(1))) void*)g,
      (__attribute__((address_space(3))) void*)l, 16, 0, 0);
}

#define BAR_VMN(N)                                        \
  do {                                                    \
    asm volatile("s_waitcnt vmcnt(" #N ")" ::: "memory"); \
    __builtin_amdgcn_s_barrier();                         \
    asm volatile("" ::: "memory");                        \
  } while (0)
#define BAR_VM5() BAR_VMN(5)
#define BAR_VM4() BAR_VMN(4)
#define BAR_VM2() BAR_VMN(2)
#define BAR_VM0() BAR_VMN(0)

// ------------- merged prep: conv_x (blocks 0..1023) + conv_w (1024..2047) -------------

__global__ __launch_bounds__(256) void prep(
    const float* __restrict__ x, bfu* __restrict__ xb,
    const float* __restrict__ W0, const float* __restrict__ W1,
    const float* __restrict__ W2, const float* __restrict__ W3,
    bfu* __restrict__ T0, bfu* __restrict__ T1,
    bfu* __restrict__ T2, bfu* __restrict__ T3) {
  __shared__ bfu tile[64][65];
  if (blockIdx.x < 1024) {
    // conv_x: fp32 -> bf16, vectorized
    const int n4 = (4096 * 1024) / 4;
    for (int i = blockIdx.x * 256 + threadIdx.x; i < n4; i += 1024 * 256) {
      float4 v = ((const float4*)x)[i];
      ushort4 p;
      p.x = f2bf(v.x); p.y = f2bf(v.y); p.z = f2bf(v.z); p.w = f2bf(v.w);
      ((ushort4*)xb)[i] = p;
    }
  } else {
    // conv_w: convert + transpose a 1024x1024 fp32 [k][n] -> bf16 [n][k]
    const int j = blockIdx.x - 1024;
    const int z = j >> 8, by = (j >> 4) & 15, bx = j & 15;
    const float* W; bfu* T;
    switch (z) {
      case 0:  W = W0; T = T0; break;
      case 1:  W = W1; T = T1; break;
      case 2:  W = W2; T = T2; break;
      default: W = W3; T = T3; break;
    }
    const int k0 = by * 64, n0 = bx * 64;
    const int c = threadIdx.x & 63, r4 = threadIdx.x >> 6;
#pragma unroll
    for (int i = 0; i < 16; i++) {
      int row = r4 + i * 4;  // k-local
      tile[row][c] = f2bf(W[(size_t)(k0 + row) * 1024 + n0 + c]);
    }
    __syncthreads();
#pragma unroll
    for (int i = 0; i < 16; i++) {
      int row = r4 + i * 4;  // n-local
      T[(size_t)(n0 + row) * 1024 + k0 + c] = tile[c][row];
    }
  }
}

// ======== fused QKV GEMM v2: 256x192 tile, grid 256 (1 WG/CU), 8-wave ========
// (r18 bench-proven source, unchanged)

__global__ __launch_bounds__(512) void gemm_qkv192(
    const bfu* __restrict__ A, const bfu* __restrict__ Bt,
    bfu* __restrict__ Qb, bfu* __restrict__ Kb, bfu* __restrict__ Vb) {
  __shared__ __align__(16) bfu LDS[2 * 28672];   // 112 KB
  const int bid = blockIdx.x;
  const int xcd = bid & 7, i0 = bid >> 3;        // i0 0..31
  const int ty = xcd * 2 + (i0 & 1), tx = i0 >> 1;   // ty 0..15, tx 0..15
  const int m0 = ty * 256, n0g = tx * 192;
  const int tid = threadIdx.x, wave = tid >> 6, lane = tid & 63;
  const int wr = wave >> 2, wc = wave & 3;       // wave grid 2M x 4N (128x48/wave)
  const int fr = lane & 15, fq = lane >> 4;
  const int rslot4 = fq ^ ((fr >> 1) & 3);       // T2 read-side swizzle

#define STAGE_A(bufn, ktile, kk)                                                 \
  do {                                                                           \
    _Pragma("unroll")                                                            \
    for (int j_ = 0; j_ < 2; j_++) {                                             \
      int s_ = tid + j_ * 512;                                                   \
      int r_ = s_ >> 2, cg_ = (s_ & 3) ^ ((r_ >> 1) & 3);                        \
      gld_lds16(A + (size_t)(m0 + r_) * 1024 + (ktile) * 64 + (kk) * 32 + cg_ * 8,\
                LDS + (bufn) * 28672 + (kk) * 8192 + s_ * 8);                    \
    }                                                                            \
  } while (0)
#define STAGE_B(bufn, ktile)                                                     \
  do {                                                                           \
    _Pragma("unroll")                                                            \
    for (int j_ = 0; j_ < 3; j_++) {                                             \
      int s_ = tid + j_ * 512;                                                   \
      int kk_ = (s_ >= 768) ? 1 : 0;                                             \
      int sp_ = s_ - kk_ * 768;                                                  \
      int r_ = sp_ >> 2, cg_ = (sp_ & 3) ^ ((r_ >> 1) & 3);                      \
      gld_lds16(Bt + (size_t)(n0g + r_) * 1024 + (ktile) * 64 + kk_ * 32 + cg_ * 8,\
                LDS + (bufn) * 28672 + 16384 + s_ * 8);                          \
    }                                                                            \
  } while (0)

#define READ_B(kk)                                                               \
  _Pragma("unroll")                                                              \
  for (int n = 0; n < 3; n++)                                                    \
    bfv[n] = *(const bf16x8*)&bufc_p[16384 + (kk) * 6144 +                       \
              ((wc * 48 + n * 16 + fr) * 4 + rslot4) * 8];

#define READ_A(dst, mq, kk)                                                      \
  _Pragma("unroll")                                                              \
  for (int mm = 0; mm < 4; mm++)                                                 \
    dst[mm] = *(const bf16x8*)&bufc_p[(kk) * 8192 +                              \
              ((wr * 128 + ((mq) * 4 + mm) * 16 + fr) * 4 + rslot4) * 8];

#define MFMA_Q(afv, mq)                                                          \
  __builtin_amdgcn_s_setprio(1);                                                 \
  _Pragma("unroll")                                                              \
  for (int mm = 0; mm < 4; mm++)                                                 \
    _Pragma("unroll")                                                            \
    for (int n = 0; n < 3; n++)                                                  \
      acc[(mq) * 4 + mm][n] = __builtin_amdgcn_mfma_f32_16x16x32_bf16(           \
          afv[mm], bfv[n], acc[(mq) * 4 + mm][n], 0, 0, 0);                      \
  __builtin_amdgcn_s_setprio(0);

  f32x4 acc[8][3] = {};
  STAGE_A(0, 0, 0);
  STAGE_B(0, 0);
  STAGE_A(0, 0, 1);
  BAR_VM2();

  const int NT = 16;      // K=1024 / BK=64
  for (int t = 0; t < NT; t++) {
    const int more = (t + 1 < NT);
    const bfu* bufc_p = LDS + (t & 1) * 28672;
    const int bufn = (t & 1) ^ 1;
    bf16x8 bfv[3], afA[4], afB[4];
    // ---- k-half 0 ----
    READ_B(0);
    READ_A(afA, 0, 0);
    if (more) STAGE_A(bufn, t + 1, 0);   // 2 loads
    MFMA_Q(afA, 0);
    READ_A(afB, 1, 0);
    if (more) STAGE_B(bufn, t + 1);      // 3 loads
    MFMA_Q(afB, 1);
    if (more) BAR_VM5();    // A_k1(t) landed; A_k0(t+1)+B(t+1) in flight
    else      BAR_VM0();    // last tile: drain own A_k1
    // ---- k-half 1 ----
    READ_B(1);
    READ_A(afA, 0, 1);
    if (more) STAGE_A(bufn, t + 1, 1);   // 2 loads
    MFMA_Q(afA, 0);
    READ_A(afB, 1, 1);
    MFMA_Q(afB, 1);
    if (more) BAR_VM2();    // A_k0(t+1)+B(t+1) landed; A_k1(t+1) in flight
    else      BAR_VM0();
  }
#undef STAGE_A
#undef STAGE_B
#undef READ_B
#undef READ_A
#undef MFMA_Q

  // epilogue: per-element Q|K|V straddle (col C in [0,3072))
  const float qs = 0.1803368801f;  // 0.125*log2e (Q only)
#pragma unroll
  for (int mf = 0; mf < 8; mf++)
#pragma unroll
    for (int n = 0; n < 3; n++) {
      int r = m0 + wr * 128 + mf * 16 + fq * 4;      // global row
      int C = n0g + wc * 48 + n * 16 + fr;           // global col 0..3071
      int z = C >> 10, cwm = C & 1023;
      int b = r >> 11, tt = r & 2047, h = cwm >> 6, d = cwm & 63;
      if (z == 0) {
        size_t base = ((size_t)(b * 16 + h) * 2048 + tt) * 64 + d;
#pragma unroll
        for (int i = 0; i < 4; i++)
          Qb[base + (size_t)i * 64] = f2bf(acc[mf][n][i] * qs);
      } else if (z == 1) {
        size_t base = ((size_t)(b * 16 + h) * 2048 + tt) * 64 + d;
#pragma unroll
        for (int i = 0; i < 4; i++)
          Kb[base + (size_t)i * 64] = f2bf(acc[mf][n][i]);
      } else {
        size_t base = ((size_t)(b * 16 + h) * 64 + d) * 2048 + tt;
        ushort4 p;
        p.x = f2bf(acc[mf][n][0]); p.y = f2bf(acc[mf][n][1]);
        p.z = f2bf(acc[mf][n][2]); p.w = f2bf(acc[mf][n][3]);
        *(ushort4*)&Vb[base] = p;
      }
    }
}

// ======== output projection v2: 128^2 tile, 8-wave, 4-phase/K-tile ========
// (r16 bench-proven source, unchanged)

__global__ __launch_bounds__(512) void gemm_proj(
    const bfu* __restrict__ A, const bfu* __restrict__ Bt,
    const float* __restrict__ bias, float* __restrict__ out) {
  __shared__ __align__(16) bfu LDS[2 * 16384];   // 64 KB
  const int bid = blockIdx.x;
  const int xcd = bid & 7, i0 = bid >> 3;        // i0 0..31
  const int tx = i0 >> 2, ty = xcd * 4 + (i0 & 3);   // tx 0..7, ty 0..31
  const int m0 = ty * 128, n0 = tx * 128;
  const int tid = threadIdx.x, wave = tid >> 6, lane = tid & 63;
  const int wr = wave >> 1, wc = wave & 1;       // wave grid 4M x 2N
  const int fr = lane & 15, fq = lane >> 4;
  const int rslot4 = fq ^ ((fr >> 1) & 3);       // T2 read-side swizzle

#define STAGE_HT(bufn, ktile, isB, kk)                                           \
  do {                                                                           \
    const bfu* srcb = (isB) ? Bt + (size_t)n0 * 1024 : A + (size_t)m0 * 1024;    \
    bfu* dstb = LDS + (bufn) * 16384 + ((isB) ? 8192 : 0) + (kk) * 4096;         \
    int r_ = tid >> 2, cg_ = (tid & 3) ^ ((r_ >> 1) & 3);                        \
    gld_lds16(srcb + (size_t)r_ * 1024 + (ktile) * 64 + (kk) * 32 + cg_ * 8,     \
              dstb + tid * 8);                                                   \
  } while (0)

#define READ_B(kk)                                                               \
  _Pragma("unroll")                                                              \
  for (int n = 0; n < 4; n++)                                                    \
    bfv[n] = *(const bf16x8*)&bufc_p[8192 + (kk) * 4096 +                        \
              ((wc * 64 + n * 16 + fr) * 4 + rslot4) * 8];

#define READ_A(kk)                                                               \
  _Pragma("unroll")                                                              \
  for (int mm = 0; mm < 2; mm++)                                                 \
    af[mm] = *(const bf16x8*)&bufc_p[(kk) * 4096 +                               \
              ((wr * 32 + mm * 16 + fr) * 4 + rslot4) * 8];

#define MFMA_H(nq)                                                               \
  __builtin_amdgcn_s_setprio(1);                                                 \
  _Pragma("unroll")                                                              \
  for (int mm = 0; mm < 2; mm++)                                                 \
    _Pragma("unroll")                                                            \
    for (int n = 0; n < 2; n++)                                                  \
      acc[mm][(nq) * 2 + n] = __builtin_amdgcn_mfma_f32_16x16x32_bf16(           \
          af[mm], bfv[(nq) * 2 + n], acc[mm][(nq) * 2 + n], 0, 0, 0);            \
  __builtin_amdgcn_s_setprio(0);

  f32x4 acc[2][4] = {};
  STAGE_HT(0, 0, 0, 0);   // A_k0
  STAGE_HT(0, 0, 1, 0);   // B_k0
  STAGE_HT(0, 0, 0, 1);   // A_k1
  STAGE_HT(0, 0, 1, 1);   // B_k1
  BAR_VM2();              // A_k0,B_k0 landed; A_k1,B_k1 in flight

  const int NT = 16;      // K=1024 / BK=64
  for (int t = 0; t < NT; t++) {
    const int more = (t + 1 < NT);
    const bfu* bufc_p = LDS + (t & 1) * 16384;
    const int bufn = (t & 1) ^ 1;
    bf16x8 bfv[4], af[2];
    // ---- k-half 0 ----
    READ_B(0);
    READ_A(0);
    if (more) STAGE_HT(bufn, t + 1, 0, 0);   // A_k0(t+1)
    MFMA_H(0);
    if (more) STAGE_HT(bufn, t + 1, 1, 0);   // B_k0(t+1)
    MFMA_H(1);
    if (more) BAR_VM2();    // A_k1,B_k1(t) landed; k0(t+1) in flight
    else      BAR_VM0();    // last tile: drain own k1 halves
    // ---- k-half 1 ----
    READ_B(1);
    READ_A(1);
    if (more) STAGE_HT(bufn, t + 1, 0, 1);   // A_k1(t+1)
    MFMA_H(0);
    if (more) STAGE_HT(bufn, t + 1, 1, 1);   // B_k1(t+1)
    MFMA_H(1);
    BAR_VM2();              // A_k0,B_k0(t+1) landed; k1(t+1) in flight
  }
#undef STAGE_HT
#undef READ_B
#undef READ_A
#undef MFMA_H

  // epilogue: fp32 + bias
#pragma unroll
  for (int mm = 0; mm < 2; mm++)
#pragma unroll
    for (int n = 0; n < 4; n++) {
      int r = m0 + wr * 32 + mm * 16 + fq * 4;
      int c = n0 + wc * 64 + n * 16 + fr;
      float bv = bias[c];
#pragma unroll
      for (int i = 0; i < 4; i++)
        out[(size_t)(r + i) * 1024 + c] = acc[mm][n][i] + bv;
    }
}

// ---- flash attention (causal) v11: split-K schedule + TRIPLE-buffer counted
// vmcnt with per-phase stage interleave (r16 bench-proven source, unchanged).

__global__ __launch_bounds__(256) void attn_fwd(
    const bfu* __restrict__ Q, const bfu* __restrict__ K,
    const bfu* __restrict__ Vt, bfu* __restrict__ Ob,
    bfu* __restrict__ PO, float* __restrict__ PM, float* __restrict__ PL) {
  __shared__ __align__(16) bfu Ks[3][4096];   // 8 KB each buf (64 keys x 64 d)
  __shared__ __align__(16) bfu Vs[3][4096];
  const int bid = blockIdx.x;
  const int xcd = bid & 7, i0 = bid >> 3;        // i0 0..127
  const int slot = i0 >> 5, cuL = i0 & 31;       // slot = dispatch pass
  const int head = cuL >> 3, cu8 = cuL & 7;
  const int hb = xcd * 4 + head;                 // head instance (= b*16+h)
  int qb, mode;                                  // mode 0=full,1=half0,2=half1
  if (slot < 2)      { qb = 15 - cu8; mode = slot + 1; }
  else if (cu8 < 4)  { if (slot == 3) return; qb = cu8; mode = 0; }
  else               { qb = cu8; mode = slot - 1; }
  const int kb0   = (mode == 2) ? (qb + 1) : 0;
  const int kbmax = (mode == 1) ? qb : (2 * qb + 1);
  const int tid = threadIdx.x, wave = tid >> 6, lane = tid & 63;
  const int q31 = lane & 31, hi = lane >> 5;
  const bfu* Qh = Q  + (size_t)hb * 2048 * 64;
  const bfu* Kh = K  + (size_t)hb * 2048 * 64;
  const bfu* Vh = Vt + (size_t)hb * 64 * 2048;
  const int b = hb >> 4, h = hb & 15;
  const int q0w = qb * 128 + wave * 32;          // this wave's 32 q rows
  const int qg = q0w + q31;

  const int r0 = tid >> 3, r1 = (256 + tid) >> 3;
  const int c0 = (tid & 7) ^ (r0 & 7), c1 = (tid & 7) ^ (r1 & 7);
#define STAGE_K(bufi, kbase)                                                          \
  do {                                                                                \
    gld_lds16(Kh + (size_t)((kbase) + r0) * 64 + c0 * 8, &Ks[bufi][tid * 8]);         \
    gld_lds16(Kh + (size_t)((kbase) + r1) * 64 + c1 * 8, &Ks[bufi][(256 + tid) * 8]); \
  } while (0)
#define STAGE_V(bufi, kbase)                                                          \
  do {                                                                                \
    gld_lds16(Vh + (size_t)r0 * 2048 + (kbase) + c0 * 8, &Vs[bufi][tid * 8]);         \
    gld_lds16(Vh + (size_t)r1 * 2048 + (kbase) + c1 * 8, &Vs[bufi][(256 + tid) * 8]); \
  } while (0)

  bf16x8 qv[4];
#pragma unroll
  for (int c = 0; c < 4; c++)
    qv[c] = *(const bf16x8*)&Qh[(size_t)(q0w + q31) * 64 + c * 16 + hi * 8];

  bf16x8 onesv;
#pragma unroll
  for (int j = 0; j < 8; j++) onesv[j] = (short)0x3F80;  // bf16 1.0

  f32x16 o0 = {}, o1 = {}, lac = {};
  float m = -1e30f;

  STAGE_K(0, kb0 * 64);
  STAGE_V(0, kb0 * 64);
  STAGE_K(1, (kb0 + 1) * 64);
  STAGE_V(1, (kb0 + 1) * 64);
  BAR_VM4();   // tile kb0 landed; kb0+1 in flight

  for (int kb = kb0; kb <= kbmax; kb++) {
    const int idx = kb - kb0;
    const int cur = idx % 3, nxt = (idx + 2) % 3;
    const int pre = (kb + 2 <= kbmax);
    const int kbase = kb * 64;
    const int active = (kbase <= q0w + 31);      // wave has unmasked work
    const bfu* KsC = Ks[cur];
    const bfu* VsC = Vs[cur];
    // ---- phase 1: stage K(kb+2) early, then QK^T + softmax ----
    if (pre) STAGE_K(nxt, (kb + 2) * 64);
    u32 W0[8], W1[8];
    if (active) {
      f32x16 s0 = {}, s1 = {};
#pragma unroll
      for (int c = 0; c < 4; c++) {
        const int g = 2 * c + hi;
        bf16x8 kf0 = *(const bf16x8*)&KsC[(q31 * 8 + (g ^ (q31 & 7))) * 8];
        bf16x8 kf1 = *(const bf16x8*)&KsC[((32 + q31) * 8 + (g ^ (q31 & 7))) * 8];
        s0 = __builtin_amdgcn_mfma_f32_32x32x16_bf16(kf0, qv[c], s0, 0, 0, 0);
        s1 = __builtin_amdgcn_mfma_f32_32x32x16_bf16(kf1, qv[c], s1, 0, 0, 0);
      }
      if (kbase + 63 > q0w) {  // tile crosses diagonal: causal mask
#pragma unroll
        for (int r = 0; r < 16; r++) {
          int krow = (r & 3) + 8 * (r >> 2) + 4 * hi;
          if (kbase + krow > qg)      s0[r] = -1e30f;
          if (kbase + 32 + krow > qg) s1[r] = -1e30f;
        }
      }
      float pm = s0[0];
#pragma unroll
      for (int r = 1; r < 16; r++) pm = fmaxf(pm, s0[r]);
#pragma unroll
      for (int r = 0; r < 16; r++) pm = fmaxf(pm, s1[r]);
      pm = fmaxf(pm, __shfl_xor(pm, 32));
      if (!__all(pm <= m + 8.0f)) {
        float mn = fmaxf(m, pm);
        float al = __builtin_amdgcn_exp2f(m - mn);
        m = mn;
#pragma unroll
        for (int r = 0; r < 16; r++) {
          float alq = __shfl(al, (r & 3) + 8 * (r >> 2) + 4 * hi);
          o0[r] *= alq; o1[r] *= alq; lac[r] *= alq;
        }
      }
#pragma unroll
      for (int w = 0; w < 8; w++) {
        float a0 = __builtin_amdgcn_exp2f(s0[2 * w] - m);
        float a1 = __builtin_amdgcn_exp2f(s0[2 * w + 1] - m);
        asm("v_cvt_pk_bf16_f32 %0, %1, %2" : "=v"(W0[w]) : "v"(a0), "v"(a1));
        float b0 = __builtin_amdgcn_exp2f(s1[2 * w] - m);
        float b1 = __builtin_amdgcn_exp2f(s1[2 * w + 1] - m);
        asm("v_cvt_pk_bf16_f32 %0, %1, %2" : "=v"(W1[w]) : "v"(b0), "v"(b1));
      }
    }
    // ---- phase 2: stage V(kb+2) early, then PV + l ----
    if (pre) STAGE_V(nxt, (kb + 2) * 64);
    if (active) {
      __builtin_amdgcn_s_setprio(1);
#pragma unroll
      for (int c = 0; c < 4; c++) {
        const u32* Wsel = (c < 2) ? W0 : W1;
        const int w0 = 4 * (c & 1);
        u32 t0 = Wsel[w0],     t2 = Wsel[w0 + 2];
        u32 t1 = Wsel[w0 + 1], t3 = Wsel[w0 + 3];
        asm("v_permlane32_swap_b32 %0, %1" : "+v"(t0), "+v"(t2));
        asm("v_permlane32_swap_b32 %0, %1" : "+v"(t1), "+v"(t3));
        union { u32 u[4]; bf16x8 v; } pa;
        pa.u[0] = t0; pa.u[1] = t1; pa.u[2] = t2; pa.u[3] = t3;
        const int g = 2 * c + hi;
        bf16x8 vb0 = *(const bf16x8*)&VsC[(q31 * 8 + (g ^ (q31 & 7))) * 8];
        bf16x8 vb1 = *(const bf16x8*)&VsC[((32 + q31) * 8 + (g ^ (q31 & 7))) * 8];
        o0  = __builtin_amdgcn_mfma_f32_32x32x16_bf16(pa.v, vb0,   o0,  0, 0, 0);
        o1  = __builtin_amdgcn_mfma_f32_32x32x16_bf16(pa.v, vb1,   o1,  0, 0, 0);
        lac = __builtin_amdgcn_mfma_f32_32x32x16_bf16(pa.v, onesv, lac, 0, 0, 0);
      }
      __builtin_amdgcn_s_setprio(0);
    }
    // barrier: tile kb+1 landed (FIFO), tile kb+2's 4 loads stay in flight.
    if (pre) BAR_VM4();
    else     BAR_VM0();   // tail: drain remaining stages
  }
#undef STAGE_K
#undef STAGE_V

  if (mode == 0) {
    // direct epilogue: Ob[b*2048+t][h*64+d]
#pragma unroll
    for (int r = 0; r < 16; r++) {
      int t = q0w + (r & 3) + 8 * (r >> 2) + 4 * hi;
      float inv = 1.0f / lac[r];
      size_t base = (size_t)(b * 2048 + t) * 1024 + h * 64;
      Ob[base + q31]      = f2bf(o0[r] * inv);
      Ob[base + 32 + q31] = f2bf(o1[r] * inv);
    }
  } else {
    // partial epilogue: p in [0,768); o as bf16 [128][64], m/l fp32 [128]
    const int p = (hb * 12 + (qb - 4)) * 2 + (mode - 1);
    bfu*   po = PO + (size_t)p * 8192;
    float* pmv = PM + p * 128;
    float* plv = PL + p * 128;
    pmv[wave * 32 + q31] = m;
#pragma unroll
    for (int r = 0; r < 16; r++) {
      int rm = (r & 3) + 8 * (r >> 2) + 4 * hi;
      plv[wave * 32 + rm] = lac[r];
      po[(wave * 32 + rm) * 64 + q31]      = f2bf(o0[r]);
      po[(wave * 32 + rm) * 64 + 32 + q31] = f2bf(o1[r]);
    }
  }
}

// combine the two equal halves for qb>=4: 384 WGs = (hb, qb-4).
__global__ __launch_bounds__(256) void attn_comb(
    const bfu* __restrict__ PO, const float* __restrict__ PM,
    const float* __restrict__ PL, bfu* __restrict__ Ob) {
  const int g = blockIdx.x;            // 0..383
  const int hb = g / 12, j = g % 12, qb = j + 4;
  const int b = hb >> 4, h = hb & 15;
  const int p0 = g * 2, p1 = p0 + 1;
  const int tid = threadIdx.x;
  const int r = tid >> 1, ch = tid & 1;          // row 0..127, col-half
  float m0 = PM[p0 * 128 + r], m1 = PM[p1 * 128 + r];
  float l0 = PL[p0 * 128 + r], l1 = PL[p1 * 128 + r];
  float ms = fmaxf(m0, m1);
  float f0 = __builtin_amdgcn_exp2f(m0 - ms);
  float f1 = __builtin_amdgcn_exp2f(m1 - ms);
  float inv = 1.0f / (l0 * f0 + l1 * f1);
  const bfu* a0 = PO + (size_t)p0 * 8192 + r * 64 + ch * 32;
  const bfu* a1 = PO + (size_t)p1 * 8192 + r * 64 + ch * 32;
  const int t = qb * 128 + r;
  bfu* ob = Ob + (size_t)(b * 2048 + t) * 1024 + h * 64 + ch * 32;
#pragma unroll
  for (int k = 0; k < 4; k++) {
    bf16x8 v0 = *(const bf16x8*)(a0 + k * 8);
    bf16x8 v1 = *(const bf16x8*)(a1 + k * 8);
    bf16x8 vo;
#pragma unroll
    for (int e = 0; e < 8; e++) {
      float acc = bf2f((bfu)(unsigned short)v0[e]) * f0 +
                  bf2f((bfu)(unsigned short)v1[e]) * f1;
      vo[e] = (short)f2bf(acc * inv);
    }
    *(bf16x8*)(ob + k * 8) = vo;
  }
}

// ---------------- launch ----------------

extern "C" void kernel_launch(void* const* d_in, const int* in_sizes, int n_in,
                              void* d_out, int out_size, void* d_ws, size_t ws_size,
                              hipStream_t stream) {
  const float* x  = (const float*)d_in[0];
  const float* Wk = (const float*)d_in[1];  // note dict order: Wk before Wq!
  const float* Wq = (const float*)d_in[2];
  const float* Wv = (const float*)d_in[3];
  const float* Wp = (const float*)d_in[4];
  const float* bp = (const float*)d_in[5];
  char* ws = (char*)d_ws;
  bfu* xb  = (bfu*)(ws);
  bfu* Wqt = (bfu*)(ws + ( 8u << 20));   // start of contiguous [3072][1024] B^T
  bfu* Wkt = (bfu*)(ws + (10u << 20));
  bfu* Wvt = (bfu*)(ws + (12u << 20));
  bfu* Wpt = (bfu*)(ws + (14u << 20));
  bfu* Qb  = (bfu*)(ws + (16u << 20));
  bfu* Kb  = (bfu*)(ws + (24u << 20));
  bfu* Vb  = (bfu*)(ws + (32u << 20));
  bfu* Ab  = (bfu*)(ws + (40u << 20));
  bfu*   PO = (bfu*)(ws);                         // 768 x 8192 bf16 = 12.6 MB
  float* PM = (float*)(ws + (13u << 20));         // 768 x 128 fp32
  float* PL = (float*)(ws + (13u << 20) + (512u << 10));  // +0.5 MB
  float* out = (float*)d_out;

  prep<<<2048, 256, 0, stream>>>(x, xb, Wq, Wk, Wv, Wp, Wqt, Wkt, Wvt, Wpt);
  gemm_qkv192<<<256, 512, 0, stream>>>(xb, Wqt, Qb, Kb, Vb);
  attn_fwd<<<1024, 256, 0, stream>>>(Qb, Kb, Vb, Ab, PO, PM, PL);
  attn_comb<<<384, 256, 0, stream>>>(PO, PM, PL, Ab);
  gemm_proj<<<256, 512, 0, stream>>>(Ab, Wpt, bp, out);
}